// Round 24
// baseline (224.794 us; speedup 1.0000x reference)
//
#include <hip/hip_runtime.h>
#include <math.h>

#define NA 2048
#define NB 1024
#define NC 1024
#define NN 4096
#define DD 128
#define HHH 4
#define CCC 32
#define E_AB 65536
#define E_AC 32768
#define E_CB 32768
#define E_HET 131072
#define E_TOT 135168
#define EPSV 1e-5f
#define SCALEV 0.17677669529663687f
#define KSLICES 4
#define KSLEN 1024
#define GCHUNK 256

typedef __attribute__((ext_vector_type(8))) short bf16x8;
typedef __attribute__((ext_vector_type(4))) float f32x4;

static __device__ __forceinline__ unsigned short f2bf(float x) {
    union { float f; unsigned int u; } v; v.f = x;
    unsigned int r = v.u + 0x7FFF + ((v.u >> 16) & 1);
    return (unsigned short)(r >> 16);
}

// ---------------- generic tiled GEMM + optional bf16-pack epilogue + optional BN accumulate ----
__global__ __launch_bounds__(256) void gemm_kernel(
    const float* __restrict__ A, const float* __restrict__ B,
    const float* __restrict__ bias, const float* __restrict__ res,
    float* __restrict__ C, int M, int Nout, int K, int transB, int relu,
    float* __restrict__ bnout,
    unsigned short* __restrict__ Qb, unsigned short* __restrict__ Kb,
    unsigned short* __restrict__ Vt)
{
    __shared__ float As[128][64];
    __shared__ float Bs[128][64];
    int t = threadIdx.x;
    int tx = t & 15, ty = t >> 4;
    int m0 = blockIdx.y * 64, n0 = blockIdx.x * 64;
    float acc[4][4] = {{0.f}};
    for (int k0 = 0; k0 < K; k0 += 128) {
        {
            int r = t & 63, kq = (t >> 6) << 2;
            const float* Ap = A + (size_t)(m0 + r) * K + k0 + kq;
            #pragma unroll
            for (int i = 0; i < 8; i++) {
                float4 v = *(const float4*)(Ap + i * 16);
                As[kq + i * 16 + 0][r] = v.x;
                As[kq + i * 16 + 1][r] = v.y;
                As[kq + i * 16 + 2][r] = v.z;
                As[kq + i * 16 + 3][r] = v.w;
            }
        }
        if (!transB) {
            int kk = t >> 4, c4 = (t & 15) << 2;
            #pragma unroll
            for (int i = 0; i < 8; i++) {
                float4 v = *(const float4*)(B + (size_t)(k0 + kk + i * 16) * Nout + n0 + c4);
                *(float4*)&Bs[kk + i * 16][c4] = v;
            }
        } else {
            int c = t & 63, kq = (t >> 6) << 2;
            const float* Bp = B + (size_t)(n0 + c) * K + k0 + kq;
            #pragma unroll
            for (int i = 0; i < 8; i++) {
                float4 v = *(const float4*)(Bp + i * 16);
                Bs[kq + i * 16 + 0][c] = v.x;
                Bs[kq + i * 16 + 1][c] = v.y;
                Bs[kq + i * 16 + 2][c] = v.z;
                Bs[kq + i * 16 + 3][c] = v.w;
            }
        }
        __syncthreads();
        #pragma unroll 8
        for (int k = 0; k < 128; k++) {
            float4 a = *(const float4*)&As[k][ty << 2];
            float4 b = *(const float4*)&Bs[k][tx << 2];
            acc[0][0] = fmaf(a.x, b.x, acc[0][0]);
            acc[0][1] = fmaf(a.x, b.y, acc[0][1]);
            acc[0][2] = fmaf(a.x, b.z, acc[0][2]);
            acc[0][3] = fmaf(a.x, b.w, acc[0][3]);
            acc[1][0] = fmaf(a.y, b.x, acc[1][0]);
            acc[1][1] = fmaf(a.y, b.y, acc[1][1]);
            acc[1][2] = fmaf(a.y, b.z, acc[1][2]);
            acc[1][3] = fmaf(a.y, b.w, acc[1][3]);
            acc[2][0] = fmaf(a.z, b.x, acc[2][0]);
            acc[2][1] = fmaf(a.z, b.y, acc[2][1]);
            acc[2][2] = fmaf(a.z, b.z, acc[2][2]);
            acc[2][3] = fmaf(a.z, b.w, acc[2][3]);
            acc[3][0] = fmaf(a.w, b.x, acc[3][0]);
            acc[3][1] = fmaf(a.w, b.y, acc[3][1]);
            acc[3][2] = fmaf(a.w, b.z, acc[3][2]);
            acc[3][3] = fmaf(a.w, b.w, acc[3][3]);
        }
        __syncthreads();
    }
    if (Qb) {
        #pragma unroll
        for (int i = 0; i < 4; i++) {
            int r = m0 + (ty << 2) + i;
            #pragma unroll
            for (int j = 0; j < 4; j++) {
                int cc = n0 + (tx << 2) + j;
                float v = acc[i][j] + bias[cc];
                if (cc < 128) {
                    Qb[(cc >> 5) * 131072 + r * 32 + (cc & 31)] = f2bf(v * SCALEV);
                } else if (cc < 256) {
                    int d = cc - 128;
                    Kb[(d >> 5) * 131072 + r * 32 + (d & 31)] = f2bf(v);
                } else {
                    int d = cc - 256;
                    Vt[(d >> 5) * 131072 + (d & 31) * 4096 + r] = f2bf(v);
                }
            }
        }
        return;
    }
    float colsum[4] = {0.f, 0.f, 0.f, 0.f};
    float colsq[4] = {0.f, 0.f, 0.f, 0.f};
    #pragma unroll
    for (int i = 0; i < 4; i++) {
        int r = m0 + (ty << 2) + i;
        #pragma unroll
        for (int j = 0; j < 4; j++) {
            int cc = n0 + (tx << 2) + j;
            float v = acc[i][j];
            if (bias) v += bias[cc];
            if (res) v += res[(size_t)r * Nout + cc];
            if (relu) v = fmaxf(v, 0.f);
            C[(size_t)r * Nout + cc] = v;
            colsum[j] += v;
            colsq[j] = fmaf(v, v, colsq[j]);
        }
    }
    if (bnout) {
        __syncthreads();
        #pragma unroll
        for (int j = 0; j < 4; j++) {
            As[(tx << 2) + j][ty] = colsum[j];
            Bs[(tx << 2) + j][ty] = colsq[j];
        }
        __syncthreads();
        if (t < 64) {
            float s = 0.f, q = 0.f;
            #pragma unroll
            for (int k = 0; k < 16; k++) { s += As[t][k]; q += Bs[t][k]; }
            atomicAdd(&bnout[n0 + t], s);
            atomicAdd(&bnout[128 + n0 + t], q);
        }
    }
}

// ---------------- MFMA bf16 GEMM: C[M,Nout]=A[M,K]@B[K,Nout] (+bias,+res,relu,bn) ----------
__global__ __launch_bounds__(256) void mgemm_kernel(
    const float* __restrict__ A, const float* __restrict__ B,
    const float* __restrict__ bias, const float* __restrict__ res,
    float* __restrict__ C, int M, int Nout, int K, int relu,
    float* __restrict__ bnout)
{
    __shared__ unsigned short Asb[64][136];
    __shared__ unsigned short Bsb[64][136];
    int t = threadIdx.x;
    int w = t >> 6, l = t & 63, lg = l >> 4, lc = l & 15;
    int m0 = blockIdx.y * 64, n0 = blockIdx.x * 64;
    f32x4 zero = {0.f, 0.f, 0.f, 0.f};
    f32x4 acc[4] = {zero, zero, zero, zero};
    for (int k0 = 0; k0 < K; k0 += 128) {
        {
            int r = t & 63, ks = w * 32;
            const float* Ap = A + (size_t)(m0 + r) * K + k0 + ks;
            #pragma unroll
            for (int i = 0; i < 8; i++) {
                float4 v = *(const float4*)(Ap + i * 4);
                unsigned int w0 = (unsigned int)f2bf(v.x) | ((unsigned int)f2bf(v.y) << 16);
                unsigned int w1 = (unsigned int)f2bf(v.z) | ((unsigned int)f2bf(v.w) << 16);
                *(unsigned int*)&Asb[r][ks + i * 4] = w0;
                *(unsigned int*)&Asb[r][ks + i * 4 + 2] = w1;
            }
        }
        {
            int kkp = t & 63;
            const float* Bp0 = B + (size_t)(k0 + kkp * 2) * Nout + n0 + w * 16;
            const float* Bp1 = Bp0 + Nout;
            #pragma unroll
            for (int j = 0; j < 16; j++) {
                unsigned int wv = (unsigned int)f2bf(Bp0[j]) | ((unsigned int)f2bf(Bp1[j]) << 16);
                *(unsigned int*)&Bsb[w * 16 + j][kkp * 2] = wv;
            }
        }
        __syncthreads();
        #pragma unroll
        for (int ksub = 0; ksub < 4; ksub++) {
            bf16x8 af = *(const bf16x8*)&Asb[w * 16 + lc][ksub * 32 + lg * 8];
            #pragma unroll
            for (int nsub = 0; nsub < 4; nsub++) {
                bf16x8 bfr = *(const bf16x8*)&Bsb[nsub * 16 + lc][ksub * 32 + lg * 8];
                acc[nsub] = __builtin_amdgcn_mfma_f32_16x16x32_bf16(af, bfr, acc[nsub], 0, 0, 0);
            }
        }
        __syncthreads();
    }
    float colsum[4], colsq[4];
    #pragma unroll
    for (int nsub = 0; nsub < 4; nsub++) {
        int cc = n0 + nsub * 16 + lc;
        float cs = 0.f, cq = 0.f;
        #pragma unroll
        for (int r = 0; r < 4; r++) {
            int m = m0 + w * 16 + lg * 4 + r;
            float v = acc[nsub][r];
            if (bias) v += bias[cc];
            if (res) v += res[(size_t)m * Nout + cc];
            if (relu) v = fmaxf(v, 0.f);
            C[(size_t)m * Nout + cc] = v;
            cs += v;
            cq = fmaf(v, v, cq);
        }
        colsum[nsub] = cs;
        colsq[nsub] = cq;
    }
    if (bnout) {
        __syncthreads();
        float* S1 = reinterpret_cast<float*>(&Asb[0][0]);
        float* S2 = S1 + 1024;
        #pragma unroll
        for (int nsub = 0; nsub < 4; nsub++) {
            S1[(nsub * 16 + lc) * 16 + w * 4 + lg] = colsum[nsub];
            S2[(nsub * 16 + lc) * 16 + w * 4 + lg] = colsq[nsub];
        }
        __syncthreads();
        if (t < 64) {
            float s = 0.f, q = 0.f;
            #pragma unroll
            for (int i = 0; i < 16; i++) { s += S1[t * 16 + i]; q += S2[t * 16 + i]; }
            atomicAdd(&bnout[n0 + t], s);
            atomicAdd(&bnout[128 + n0 + t], q);
        }
    }
}

// ---------------- fused 3-way input projection ----------------
__global__ __launch_bounds__(256) void proj3_kernel(
    const float* __restrict__ x_a, const float* __restrict__ Wa, const float* __restrict__ ba,
    const float* __restrict__ x_b, const float* __restrict__ Wb, const float* __restrict__ bb,
    const float* __restrict__ x_c, const float* __restrict__ Wc, const float* __restrict__ bc,
    float* __restrict__ h)
{
    __shared__ float As[128][64];
    __shared__ float Bs[128][64];
    int t = threadIdx.x;
    int tx = t & 15, ty = t >> 4;
    int by = blockIdx.y;
    const float* A; const float* B; const float* bias; int m0s, m0d;
    if (by < 32)      { A = x_a; B = Wa; bias = ba; m0s = by * 64;        m0d = m0s; }
    else if (by < 48) { A = x_b; B = Wb; bias = bb; m0s = (by - 32) * 64; m0d = 2048 + m0s; }
    else              { A = x_c; B = Wc; bias = bc; m0s = (by - 48) * 64; m0d = 3072 + m0s; }
    int n0 = blockIdx.x * 64;
    float acc[4][4] = {{0.f}};
    {
        int r = t & 63, kq = (t >> 6) << 2;
        const float* Ap = A + (size_t)(m0s + r) * 128 + kq;
        #pragma unroll
        for (int i = 0; i < 8; i++) {
            float4 v = *(const float4*)(Ap + i * 16);
            As[kq + i * 16 + 0][r] = v.x;
            As[kq + i * 16 + 1][r] = v.y;
            As[kq + i * 16 + 2][r] = v.z;
            As[kq + i * 16 + 3][r] = v.w;
        }
        int kk = t >> 4, c4 = (t & 15) << 2;
        #pragma unroll
        for (int i = 0; i < 8; i++) {
            float4 v = *(const float4*)(B + (size_t)(kk + i * 16) * 128 + n0 + c4);
            *(float4*)&Bs[kk + i * 16][c4] = v;
        }
    }
    __syncthreads();
    #pragma unroll 8
    for (int k = 0; k < 128; k++) {
        float4 a = *(const float4*)&As[k][ty << 2];
        float4 b = *(const float4*)&Bs[k][tx << 2];
        acc[0][0] = fmaf(a.x, b.x, acc[0][0]);
        acc[0][1] = fmaf(a.x, b.y, acc[0][1]);
        acc[0][2] = fmaf(a.x, b.z, acc[0][2]);
        acc[0][3] = fmaf(a.x, b.w, acc[0][3]);
        acc[1][0] = fmaf(a.y, b.x, acc[1][0]);
        acc[1][1] = fmaf(a.y, b.y, acc[1][1]);
        acc[1][2] = fmaf(a.y, b.z, acc[1][2]);
        acc[1][3] = fmaf(a.y, b.w, acc[1][3]);
        acc[2][0] = fmaf(a.z, b.x, acc[2][0]);
        acc[2][1] = fmaf(a.z, b.y, acc[2][1]);
        acc[2][2] = fmaf(a.z, b.z, acc[2][2]);
        acc[2][3] = fmaf(a.z, b.w, acc[2][3]);
        acc[3][0] = fmaf(a.w, b.x, acc[3][0]);
        acc[3][1] = fmaf(a.w, b.y, acc[3][1]);
        acc[3][2] = fmaf(a.w, b.z, acc[3][2]);
        acc[3][3] = fmaf(a.w, b.w, acc[3][3]);
    }
    #pragma unroll
    for (int i = 0; i < 4; i++) {
        int r = m0d + (ty << 2) + i;
        #pragma unroll
        for (int j = 0; j < 4; j++) {
            int cc = n0 + (tx << 2) + j;
            h[(size_t)r * 128 + cc] = acc[i][j] + bias[cc];
        }
    }
}

// ---------------- GAT attention scalar scores ----------------
__global__ __launch_bounds__(256) void att_scores(
    const float* __restrict__ xp, const float* __restrict__ att_src, const float* __restrict__ att_dst,
    float* __restrict__ asv, float* __restrict__ adv)
{
    int t = blockIdx.x * 256 + threadIdx.x;
    int n = t >> 2, hh = t & 3;
    const float* row = xp + (size_t)n * 128 + hh * 32;
    float s1 = 0.f, s2 = 0.f;
    #pragma unroll
    for (int c = 0; c < 32; c++) {
        float v = row[c];
        s1 = fmaf(v, att_src[hh * 32 + c], s1);
        s2 = fmaf(v, att_dst[hh * 32 + c], s2);
    }
    asv[t] = s1;
    adv[t] = s2;
}

// ---------------- CSR build ----------------
__global__ __launch_bounds__(256) void edge_hist(
    const int* __restrict__ ab_d, const int* __restrict__ ac_d, const int* __restrict__ cb_d,
    int* __restrict__ cnt)
{
    int e = blockIdx.x * 256 + threadIdx.x;
    int d;
    if (e < E_AB) d = ab_d[e] + NA;
    else if (e < E_AB + E_AC) d = ac_d[e - E_AB] + NA + NB;
    else if (e < E_HET) d = cb_d[e - E_AB - E_AC] + NA;
    else d = e - E_HET;
    atomicAdd(&cnt[d], 1);
}

__global__ __launch_bounds__(256) void scan_kernel(
    const int* __restrict__ cnt, int* __restrict__ rowptr, int* __restrict__ fill)
{
    __shared__ int sums[256];
    int t = threadIdx.x;
    int local[16];
    int s = 0;
    #pragma unroll
    for (int i = 0; i < 16; i++) { local[i] = s; s += cnt[t * 16 + i]; }
    sums[t] = s;
    __syncthreads();
    for (int d = 1; d < 256; d <<= 1) {
        int v = (t >= d) ? sums[t - d] : 0;
        __syncthreads();
        sums[t] += v;
        __syncthreads();
    }
    int base = sums[t] - s;
    #pragma unroll
    for (int i = 0; i < 16; i++) {
        int v = base + local[i];
        rowptr[t * 16 + i] = v;
        fill[t * 16 + i] = v;
    }
    if (t == 255) rowptr[NN] = sums[255];
}

__global__ __launch_bounds__(256) void edge_scatter(
    const int* __restrict__ ab_s, const int* __restrict__ ab_d,
    const int* __restrict__ ac_s, const int* __restrict__ ac_d,
    const int* __restrict__ cb_s, const int* __restrict__ cb_d,
    int* __restrict__ fill, int* __restrict__ csr)
{
    int e = blockIdx.x * 256 + threadIdx.x;
    int s, d;
    if (e < E_AB) { s = ab_s[e]; d = ab_d[e] + NA; }
    else if (e < E_AB + E_AC) { int i = e - E_AB; s = ac_s[i]; d = ac_d[i] + NA + NB; }
    else if (e < E_HET) { int i = e - E_AB - E_AC; s = cb_s[i] + NA + NB; d = cb_d[i] + NA; }
    else { s = e - E_HET; d = s; }
    int pos = atomicAdd(&fill[d], 1);
    csr[pos] = s;
}

// ---------------- GAT gather ----------------
__global__ __launch_bounds__(128) void gat_gather(
    const float* __restrict__ xp, const float* __restrict__ asv, const float* __restrict__ adv,
    const int* __restrict__ rowptr, const int* __restrict__ csr,
    const float* __restrict__ b_gat, const float* __restrict__ hres, float* __restrict__ y)
{
    __shared__ int sidx[GCHUNK];
    __shared__ float salpha[4][GCHUNK];
    int n = blockIdx.x;
    int t = threadIdx.x;
    int hh = t >> 5, lane = t & 31;
    int beg = rowptr[n], end = rowptr[n + 1];
    int deg = end - beg;
    float ad = adv[n * 4 + hh];
    float mh = -1e30f;
    for (int j = beg + lane; j < end; j += 32) {
        int s = csr[j];
        float e = asv[s * 4 + hh] + ad;
        e = (e > 0.f) ? e : 0.2f * e;
        mh = fmaxf(mh, e);
    }
    mh = fmaxf(mh, __shfl_xor(mh, 1));
    mh = fmaxf(mh, __shfl_xor(mh, 2));
    mh = fmaxf(mh, __shfl_xor(mh, 4));
    mh = fmaxf(mh, __shfl_xor(mh, 8));
    mh = fmaxf(mh, __shfl_xor(mh, 16));
    float dn = 0.f;
    for (int j = beg + lane; j < end; j += 32) {
        int s = csr[j];
        float e = asv[s * 4 + hh] + ad;
        e = (e > 0.f) ? e : 0.2f * e;
        dn += __expf(e - mh);
    }
    dn += __shfl_xor(dn, 1);
    dn += __shfl_xor(dn, 2);
    dn += __shfl_xor(dn, 4);
    dn += __shfl_xor(dn, 8);
    dn += __shfl_xor(dn, 16);
    float inv = 1.f / dn;
    float acc = 0.f;
    int c = lane;
    for (int c0 = 0; c0 < deg; c0 += GCHUNK) {
        int cn = min(GCHUNK, deg - c0);
        for (int jj = lane; jj < cn; jj += 32) {
            int s = csr[beg + c0 + jj];
            if (hh == 0) sidx[jj] = s;
            float e = asv[s * 4 + hh] + ad;
            e = (e > 0.f) ? e : 0.2f * e;
            salpha[hh][jj] = __expf(e - mh) * inv;
        }
        __syncthreads();
        #pragma unroll 4
        for (int j = 0; j < cn; j++) {
            acc = fmaf(salpha[hh][j], xp[(size_t)sidx[j] * 128 + hh * 32 + c], acc);
        }
        __syncthreads();
    }
    y[(size_t)n * 128 + t] = acc + b_gat[t] + hres[(size_t)n * 128 + t];
}

// ---------------- BatchNorm accumulate (for gat_gather output only) ----------------
__global__ __launch_bounds__(256) void bn_acc(
    const float* __restrict__ x, float* __restrict__ out)
{
    int t = threadIdx.x;
    int c = t & 127, rh = t >> 7;
    int r0 = blockIdx.x * 128;   // grid 32
    float s = 0.f, s2 = 0.f;
    for (int r = rh; r < 128; r += 2) {
        float v = x[(size_t)(r0 + r) * 128 + c];
        s += v;
        s2 = fmaf(v, v, s2);
    }
    __shared__ float bs[256], bq[256];
    bs[t] = s; bq[t] = s2;
    __syncthreads();
    if (t < 128) {
        atomicAdd(&out[c], bs[t] + bs[t + 128]);
        atomicAdd(&out[128 + c], bq[t] + bq[t + 128]);
    }
}

// ---------------- MFMA flash attention: 2 q-fragments per wave (K/V amortized) ----------------
// Wave owns 32 q-rows (two 16-row frags A,B); K/V frags loaded once, used by both.
// grid: ksl(4) x h(4) x qb(32) = 512 blocks, 256 threads (4 waves).
__global__ __launch_bounds__(256) void attn_kernel(
    const unsigned short* __restrict__ Qb, const unsigned short* __restrict__ Kb,
    const unsigned short* __restrict__ Vt, float* __restrict__ po,
    float* __restrict__ pm, float* __restrict__ pl)
{
    __shared__ unsigned short P16[4][2][16][72];
    int bid = blockIdx.x;
    int ksl = bid & 3;
    int h = (bid >> 2) & 3;
    int qb = bid >> 4;               // [0,32)
    int t = threadIdx.x;
    int w = t >> 6;
    int l = t & 63;
    int lg = l >> 4, lc = l & 15;
    int q0 = (qb * 4 + w) * 32;      // 32 rows per wave
    f32x4 zero = {0.f, 0.f, 0.f, 0.f};
    const unsigned short* Qh = Qb + h * 131072;
    const unsigned short* Kh = Kb + h * 131072;
    const unsigned short* Vh = Vt + h * 131072;
    bf16x8 qfA = *(const bf16x8*)(Qh + (size_t)(q0 + lc) * 32 + lg * 8);
    bf16x8 qfB = *(const bf16x8*)(Qh + (size_t)(q0 + 16 + lc) * 32 + lg * 8);
    f32x4 o0a = zero, o1a = zero, o0b = zero, o1b = zero;
    float mxA[4] = {-1e30f, -1e30f, -1e30f, -1e30f};
    float lsA[4] = {0.f, 0.f, 0.f, 0.f};
    float mxB[4] = {-1e30f, -1e30f, -1e30f, -1e30f};
    float lsB[4] = {0.f, 0.f, 0.f, 0.f};
    int kbeg = ksl * KSLEN;
    #pragma unroll 1
    for (int kt = kbeg; kt < kbeg + KSLEN; kt += 64) {
        // QK^T: K-frag loaded once, feeds both q-frags
        f32x4 sA[4], sB[4];
        #pragma unroll
        for (int sub = 0; sub < 4; sub++) {
            bf16x8 kf = *(const bf16x8*)(Kh + (size_t)(kt + sub * 16 + lc) * 32 + lg * 8);
            sA[sub] = __builtin_amdgcn_mfma_f32_16x16x32_bf16(qfA, kf, zero, 0, 0, 0);
            sB[sub] = __builtin_amdgcn_mfma_f32_16x16x32_bf16(qfB, kf, zero, 0, 0, 0);
        }
        // V-frags loaded once (hide under softmax), used by both q-frags
        bf16x8 vf[2][2];
        #pragma unroll
        for (int ks = 0; ks < 2; ks++)
            #pragma unroll
            for (int ct = 0; ct < 2; ct++)
                vf[ks][ct] = *(const bf16x8*)(Vh + (size_t)(ct * 16 + lc) * 4096 + kt + ks * 32 + lg * 8);
        // online softmax frag A
        float pA[4][4];
        #pragma unroll
        for (int r = 0; r < 4; r++) {
            float tm = fmaxf(fmaxf(sA[0][r], sA[1][r]), fmaxf(sA[2][r], sA[3][r]));
            tm = fmaxf(tm, __shfl_xor(tm, 1));
            tm = fmaxf(tm, __shfl_xor(tm, 2));
            tm = fmaxf(tm, __shfl_xor(tm, 4));
            tm = fmaxf(tm, __shfl_xor(tm, 8));
            if (tm > mxA[r]) {
                float cr = __expf(mxA[r] - tm);
                lsA[r] *= cr;
                o0a[r] *= cr;
                o1a[r] *= cr;
                mxA[r] = tm;
            }
            float rs = 0.f;
            #pragma unroll
            for (int sub = 0; sub < 4; sub++) {
                pA[sub][r] = __expf(sA[sub][r] - mxA[r]);
                rs += pA[sub][r];
            }
            rs += __shfl_xor(rs, 1);
            rs += __shfl_xor(rs, 2);
            rs += __shfl_xor(rs, 4);
            rs += __shfl_xor(rs, 8);
            lsA[r] += rs;
        }
        // online softmax frag B
        float pB[4][4];
        #pragma unroll
        for (int r = 0; r < 4; r++) {
            float tm = fmaxf(fmaxf(sB[0][r], sB[1][r]), fmaxf(sB[2][r], sB[3][r]));
            tm = fmaxf(tm, __shfl_xor(tm, 1));
            tm = fmaxf(tm, __shfl_xor(tm, 2));
            tm = fmaxf(tm, __shfl_xor(tm, 4));
            tm = fmaxf(tm, __shfl_xor(tm, 8));
            if (tm > mxB[r]) {
                float cr = __expf(mxB[r] - tm);
                lsB[r] *= cr;
                o0b[r] *= cr;
                o1b[r] *= cr;
                mxB[r] = tm;
            }
            float rs = 0.f;
            #pragma unroll
            for (int sub = 0; sub < 4; sub++) {
                pB[sub][r] = __expf(sB[sub][r] - mxB[r]);
                rs += pB[sub][r];
            }
            rs += __shfl_xor(rs, 1);
            rs += __shfl_xor(rs, 2);
            rs += __shfl_xor(rs, 4);
            rs += __shfl_xor(rs, 8);
            lsB[r] += rs;
        }
        // P (bf16) -> LDS (same-wave, no barrier)
        #pragma unroll
        for (int sub = 0; sub < 4; sub++)
            #pragma unroll
            for (int r = 0; r < 4; r++) {
                P16[w][0][lg * 4 + r][sub * 16 + lc] = f2bf(pA[sub][r]);
                P16[w][1][lg * 4 + r][sub * 16 + lc] = f2bf(pB[sub][r]);
            }
        bf16x8 paA[2], paB[2];
        #pragma unroll
        for (int ks = 0; ks < 2; ks++) {
            paA[ks] = *(const bf16x8*)(&P16[w][0][lc][ks * 32 + lg * 8]);
            paB[ks] = *(const bf16x8*)(&P16[w][1][lc][ks * 32 + lg * 8]);
        }
        #pragma unroll
        for (int ks = 0; ks < 2; ks++) {
            o0a = __builtin_amdgcn_mfma_f32_16x16x32_bf16(paA[ks], vf[ks][0], o0a, 0, 0, 0);
            o1a = __builtin_amdgcn_mfma_f32_16x16x32_bf16(paA[ks], vf[ks][1], o1a, 0, 0, 0);
            o0b = __builtin_amdgcn_mfma_f32_16x16x32_bf16(paB[ks], vf[ks][0], o0b, 0, 0, 0);
            o1b = __builtin_amdgcn_mfma_f32_16x16x32_bf16(paB[ks], vf[ks][1], o1b, 0, 0, 0);
        }
    }
    int baseA = (ksl * HHH + h) * NN + q0;
    int baseB = baseA + 16;
    #pragma unroll
    for (int r = 0; r < 4; r++) {
        size_t obA = (size_t)(baseA + lg * 4 + r) * 32;
        size_t obB = (size_t)(baseB + lg * 4 + r) * 32;
        po[obA + lc] = o0a[r];
        po[obA + 16 + lc] = o1a[r];
        po[obB + lc] = o0b[r];
        po[obB + 16 + lc] = o1b[r];
    }
    #pragma unroll
    for (int r = 0; r < 4; r++) {
        if (lc == r) {
            pm[baseA + lg * 4 + r] = mxA[r];
            pl[baseA + lg * 4 + r] = lsA[r];
            pm[baseB + lg * 4 + r] = mxB[r];
            pl[baseB + lg * 4 + r] = lsB[r];
        }
    }
}

__global__ __launch_bounds__(256) void attn_comb(
    const float* __restrict__ po, const float* __restrict__ pm, const float* __restrict__ pl,
    float* __restrict__ o_at)
{
    int idx = blockIdx.x * 256 + threadIdx.x;  // N*128
    int n = idx >> 7, hc = idx & 127, hh = hc >> 5, c = idx & 31;
    float M = -1e30f;
    #pragma unroll
    for (int s = 0; s < KSLICES; s++) M = fmaxf(M, pm[(s * HHH + hh) * NN + n]);
    float accv = 0.f, L = 0.f;
    #pragma unroll
    for (int s = 0; s < KSLICES; s++) {
        int id = (s * HHH + hh) * NN + n;
        float wgt = __expf(pm[id] - M);
        L = fmaf(wgt, pl[id], L);
        accv = fmaf(wgt, po[(size_t)id * 32 + c], accv);
    }
    o_at[idx] = accv / L;
}

// ---------------- combine; final (BN from raw sums) ----------------
__global__ __launch_bounds__(256) void combine_kernel(
    const float* __restrict__ y1, const float* __restrict__ y2,
    const float* __restrict__ stats,
    const float* __restrict__ g1, const float* __restrict__ be1,
    const float* __restrict__ g2, const float* __restrict__ be2,
    float* __restrict__ outp)
{
    int idx = blockIdx.x * 256 + threadIdx.x;
    int c = idx & 127;
    const float invn = 1.f / (float)NN;
    float mu1 = stats[c] * invn;
    float r1 = rsqrtf(stats[128 + c] * invn - mu1 * mu1 + EPSV);
    float mu2 = stats[256 + c] * invn;
    float r2 = rsqrtf(stats[384 + c] * invn - mu2 * mu2 + EPSV);
    float v1 = (y1[idx] - mu1) * r1 * g1[c] + be1[c];
    float v2 = (y2[idx] - mu2) * r2 * g2[c] + be2[c];
    outp[idx] = v1 + v2;
}

__global__ __launch_bounds__(256) void final_kernel(
    const float* __restrict__ out2, const float* __restrict__ stats,
    const float* __restrict__ g3, const float* __restrict__ be3,
    float* __restrict__ outv)
{
    int idx = blockIdx.x * 256 + threadIdx.x;
    int c = idx & 127;
    const float invn = 1.f / (float)NN;
    float mu = stats[512 + c] * invn;
    float r = rsqrtf(stats[640 + c] * invn - mu * mu + EPSV);
    outv[idx] = (out2[idx] - mu) * r * g3[c] + be3[c];
}

extern "C" void kernel_launch(void* const* d_in, const int* in_sizes, int n_in,
                              void* d_out, int out_size, void* d_ws, size_t ws_size,
                              hipStream_t stream)
{
    (void)in_sizes; (void)n_in; (void)out_size; (void)ws_size;
    const float* x_a   = (const float*)d_in[0];
    const float* x_b   = (const float*)d_in[1];
    const float* x_c   = (const float*)d_in[2];
    const int* ab_s    = (const int*)d_in[3];
    const int* ab_d    = (const int*)d_in[4];
    const int* ac_s    = (const int*)d_in[5];
    const int* ac_d    = (const int*)d_in[6];
    const int* cb_s    = (const int*)d_in[7];
    const int* cb_d    = (const int*)d_in[8];
    const float* W_in_a = (const float*)d_in[9];
    const float* b_in_a = (const float*)d_in[10];
    const float* W_in_b = (const float*)d_in[11];
    const float* b_in_b = (const float*)d_in[12];
    const float* W_in_c = (const float*)d_in[13];
    const float* b_in_c = (const float*)d_in[14];
    const float* W_gat  = (const float*)d_in[15];
    const float* att_src = (const float*)d_in[16];
    const float* att_dst = (const float*)d_in[17];
    const float* b_gat  = (const float*)d_in[18];
    const float* W_qkv  = (const float*)d_in[19];
    const float* b_qkv  = (const float*)d_in[20];
    const float* W_o    = (const float*)d_in[21];
    const float* b_o    = (const float*)d_in[22];
    const float* g1     = (const float*)d_in[23];
    const float* be1    = (const float*)d_in[24];
    const float* g2     = (const float*)d_in[25];
    const float* be2    = (const float*)d_in[26];
    const float* g3     = (const float*)d_in[27];
    const float* be3    = (const float*)d_in[28];
    const float* W_mlp1 = (const float*)d_in[29];
    const float* b_mlp1 = (const float*)d_in[30];
    const float* W_mlp2 = (const float*)d_in[31];
    const float* b_mlp2 = (const float*)d_in[32];

    float* ws   = (float*)d_ws;
    float* h    = ws + 0;          // 524288
    float* o_at = ws + 2097152;    // 524288
    float* y2   = ws + 2621440;    // 524288 (attn-time: pm/pl; later: o-proj+res)
    float* stats = ws + 3145728;   // 768 (raw sums; zeroed each launch)
    float* R    = ws + 3146496;    // reused region
    // attention-time views:
    float* po = R;                        // 4*4*4096*32 = 2097152 floats
    unsigned short* Qb = (unsigned short*)(R + 2097152);  // 262144 bf16
    unsigned short* Kb = (unsigned short*)(R + 2228224);
    unsigned short* Vt = (unsigned short*)(R + 2359296);
    float* pm = y2;                // 65536
    float* pl = y2 + 65536;        // 65536
    // post-attention view of R:
    float* xp   = R + 0;           // 524288
    float* y1   = R + 524288;      // 524288
    float* outp = R + 1048576;     // 524288
    float* hid  = R + 1572864;     // 1048576
    float* out2 = R + 2621440;     // 524288
    float* asv  = R + 3145728;     // 16384
    float* adv  = R + 3162112;     // 16384
    int* cnt    = (int*)(R + 3178496);
    int* rowptr = cnt + 4096;      // 4104 incl pad
    int* fill   = rowptr + 4104;
    int* csr    = fill + 4096;     // E_TOT

    hipMemsetAsync(stats, 0, 768 * sizeof(float), stream);

    // ---- fused input projections + qkv (qkv GEMM packs bf16 Q/K/V directly) ----
    proj3_kernel<<<dim3(2, 64), 256, 0, stream>>>(x_a, W_in_a, b_in_a, x_b, W_in_b, b_in_b, x_c, W_in_c, b_in_c, h);
    gemm_kernel<<<dim3(6, 64), 256, 0, stream>>>(h, W_qkv, b_qkv, nullptr, nullptr, NN, 384, 128, 1, 0, nullptr, Qb, Kb, Vt);
    // ---- global attention (MFMA flash, 2 q-frags/wave) ----
    attn_kernel<<<32 * HHH * KSLICES, 256, 0, stream>>>(Qb, Kb, Vt, po, pm, pl);
    attn_comb<<<NN * 128 / 256, 256, 0, stream>>>(po, pm, pl, o_at);
    gemm_kernel<<<dim3(2, 64), 256, 0, stream>>>(o_at, W_o, b_o, h, y2, NN, 128, 128, 1, 0, stats + 256, nullptr, nullptr, nullptr);
    // ---- GAT branch (R reused) ----
    gemm_kernel<<<dim3(2, 64), 256, 0, stream>>>(h, W_gat, nullptr, nullptr, xp, NN, 128, 128, 0, 0, nullptr, nullptr, nullptr, nullptr);
    att_scores<<<64, 256, 0, stream>>>(xp, att_src, att_dst, asv, adv);
    hipMemsetAsync(cnt, 0, NN * sizeof(int), stream);
    edge_hist<<<E_TOT / 256, 256, 0, stream>>>(ab_d, ac_d, cb_d, cnt);
    scan_kernel<<<1, 256, 0, stream>>>(cnt, rowptr, fill);
    edge_scatter<<<E_TOT / 256, 256, 0, stream>>>(ab_s, ab_d, ac_s, ac_d, cb_s, cb_d, fill, csr);
    gat_gather<<<NN, 128, 0, stream>>>(xp, asv, adv, rowptr, csr, b_gat, h, y1);
    bn_acc<<<32, 256, 0, stream>>>(y1, stats + 0);
    // ---- combine + MLP (MFMA bf16 GEMMs) ----
    combine_kernel<<<NN * 128 / 256, 256, 0, stream>>>(y1, y2, stats, g1, be1, g2, be2, outp);
    mgemm_kernel<<<dim3(4, 64), 256, 0, stream>>>(outp, W_mlp1, b_mlp1, nullptr, hid, NN, 256, 128, 1, nullptr);
    mgemm_kernel<<<dim3(2, 64), 256, 0, stream>>>(hid, W_mlp2, b_mlp2, outp, out2, NN, 128, 256, 0, stats + 512);
    final_kernel<<<NN * 128 / 256, 256, 0, stream>>>(out2, stats, g3, be3, (float*)d_out);
}

// Round 25
// 219.901 us; speedup vs baseline: 1.0223x; 1.0223x over previous
//
#include <hip/hip_runtime.h>
#include <math.h>

#define NA 2048
#define NB 1024
#define NC 1024
#define NN 4096
#define DD 128
#define HHH 4
#define CCC 32
#define E_AB 65536
#define E_AC 32768
#define E_CB 32768
#define E_HET 131072
#define E_TOT 135168
#define EPSV 1e-5f
#define SCALEV 0.17677669529663687f
#define KSLICES 4
#define KSLEN 1024
#define GCHUNK 256

typedef __attribute__((ext_vector_type(8))) short bf16x8;
typedef __attribute__((ext_vector_type(4))) float f32x4;

static __device__ __forceinline__ unsigned short f2bf(float x) {
    union { float f; unsigned int u; } v; v.f = x;
    unsigned int r = v.u + 0x7FFF + ((v.u >> 16) & 1);
    return (unsigned short)(r >> 16);
}

// ---------------- generic tiled GEMM + optional bf16-pack epilogue + optional BN accumulate ----
__global__ __launch_bounds__(256) void gemm_kernel(
    const float* __restrict__ A, const float* __restrict__ B,
    const float* __restrict__ bias, const float* __restrict__ res,
    float* __restrict__ C, int M, int Nout, int K, int transB, int relu,
    float* __restrict__ bnout,
    unsigned short* __restrict__ Qb, unsigned short* __restrict__ Kb,
    unsigned short* __restrict__ Vt)
{
    __shared__ float As[128][64];
    __shared__ float Bs[128][64];
    int t = threadIdx.x;
    int tx = t & 15, ty = t >> 4;
    int m0 = blockIdx.y * 64, n0 = blockIdx.x * 64;
    float acc[4][4] = {{0.f}};
    for (int k0 = 0; k0 < K; k0 += 128) {
        {
            int r = t & 63, kq = (t >> 6) << 2;
            const float* Ap = A + (size_t)(m0 + r) * K + k0 + kq;
            #pragma unroll
            for (int i = 0; i < 8; i++) {
                float4 v = *(const float4*)(Ap + i * 16);
                As[kq + i * 16 + 0][r] = v.x;
                As[kq + i * 16 + 1][r] = v.y;
                As[kq + i * 16 + 2][r] = v.z;
                As[kq + i * 16 + 3][r] = v.w;
            }
        }
        if (!transB) {
            int kk = t >> 4, c4 = (t & 15) << 2;
            #pragma unroll
            for (int i = 0; i < 8; i++) {
                float4 v = *(const float4*)(B + (size_t)(k0 + kk + i * 16) * Nout + n0 + c4);
                *(float4*)&Bs[kk + i * 16][c4] = v;
            }
        } else {
            int c = t & 63, kq = (t >> 6) << 2;
            const float* Bp = B + (size_t)(n0 + c) * K + k0 + kq;
            #pragma unroll
            for (int i = 0; i < 8; i++) {
                float4 v = *(const float4*)(Bp + i * 16);
                Bs[kq + i * 16 + 0][c] = v.x;
                Bs[kq + i * 16 + 1][c] = v.y;
                Bs[kq + i * 16 + 2][c] = v.z;
                Bs[kq + i * 16 + 3][c] = v.w;
            }
        }
        __syncthreads();
        #pragma unroll 8
        for (int k = 0; k < 128; k++) {
            float4 a = *(const float4*)&As[k][ty << 2];
            float4 b = *(const float4*)&Bs[k][tx << 2];
            acc[0][0] = fmaf(a.x, b.x, acc[0][0]);
            acc[0][1] = fmaf(a.x, b.y, acc[0][1]);
            acc[0][2] = fmaf(a.x, b.z, acc[0][2]);
            acc[0][3] = fmaf(a.x, b.w, acc[0][3]);
            acc[1][0] = fmaf(a.y, b.x, acc[1][0]);
            acc[1][1] = fmaf(a.y, b.y, acc[1][1]);
            acc[1][2] = fmaf(a.y, b.z, acc[1][2]);
            acc[1][3] = fmaf(a.y, b.w, acc[1][3]);
            acc[2][0] = fmaf(a.z, b.x, acc[2][0]);
            acc[2][1] = fmaf(a.z, b.y, acc[2][1]);
            acc[2][2] = fmaf(a.z, b.z, acc[2][2]);
            acc[2][3] = fmaf(a.z, b.w, acc[2][3]);
            acc[3][0] = fmaf(a.w, b.x, acc[3][0]);
            acc[3][1] = fmaf(a.w, b.y, acc[3][1]);
            acc[3][2] = fmaf(a.w, b.z, acc[3][2]);
            acc[3][3] = fmaf(a.w, b.w, acc[3][3]);
        }
        __syncthreads();
    }
    if (Qb) {
        #pragma unroll
        for (int i = 0; i < 4; i++) {
            int r = m0 + (ty << 2) + i;
            #pragma unroll
            for (int j = 0; j < 4; j++) {
                int cc = n0 + (tx << 2) + j;
                float v = acc[i][j] + bias[cc];
                if (cc < 128) {
                    Qb[(cc >> 5) * 131072 + r * 32 + (cc & 31)] = f2bf(v * SCALEV);
                } else if (cc < 256) {
                    int d = cc - 128;
                    Kb[(d >> 5) * 131072 + r * 32 + (d & 31)] = f2bf(v);
                } else {
                    int d = cc - 256;
                    Vt[(d >> 5) * 131072 + (d & 31) * 4096 + r] = f2bf(v);
                }
            }
        }
        return;
    }
    float colsum[4] = {0.f, 0.f, 0.f, 0.f};
    float colsq[4] = {0.f, 0.f, 0.f, 0.f};
    #pragma unroll
    for (int i = 0; i < 4; i++) {
        int r = m0 + (ty << 2) + i;
        #pragma unroll
        for (int j = 0; j < 4; j++) {
            int cc = n0 + (tx << 2) + j;
            float v = acc[i][j];
            if (bias) v += bias[cc];
            if (res) v += res[(size_t)r * Nout + cc];
            if (relu) v = fmaxf(v, 0.f);
            C[(size_t)r * Nout + cc] = v;
            colsum[j] += v;
            colsq[j] = fmaf(v, v, colsq[j]);
        }
    }
    if (bnout) {
        __syncthreads();
        #pragma unroll
        for (int j = 0; j < 4; j++) {
            As[(tx << 2) + j][ty] = colsum[j];
            Bs[(tx << 2) + j][ty] = colsq[j];
        }
        __syncthreads();
        if (t < 64) {
            float s = 0.f, q = 0.f;
            #pragma unroll
            for (int k = 0; k < 16; k++) { s += As[t][k]; q += Bs[t][k]; }
            atomicAdd(&bnout[n0 + t], s);
            atomicAdd(&bnout[128 + n0 + t], q);
        }
    }
}

// ---------------- MFMA bf16 GEMM: C[M,Nout]=A[M,K]@B[K,Nout] (+bias,+res,relu,bn) ----------
__global__ __launch_bounds__(256) void mgemm_kernel(
    const float* __restrict__ A, const float* __restrict__ B,
    const float* __restrict__ bias, const float* __restrict__ res,
    float* __restrict__ C, int M, int Nout, int K, int relu,
    float* __restrict__ bnout)
{
    __shared__ unsigned short Asb[64][136];
    __shared__ unsigned short Bsb[64][136];
    int t = threadIdx.x;
    int w = t >> 6, l = t & 63, lg = l >> 4, lc = l & 15;
    int m0 = blockIdx.y * 64, n0 = blockIdx.x * 64;
    f32x4 zero = {0.f, 0.f, 0.f, 0.f};
    f32x4 acc[4] = {zero, zero, zero, zero};
    for (int k0 = 0; k0 < K; k0 += 128) {
        {
            int r = t & 63, ks = w * 32;
            const float* Ap = A + (size_t)(m0 + r) * K + k0 + ks;
            #pragma unroll
            for (int i = 0; i < 8; i++) {
                float4 v = *(const float4*)(Ap + i * 4);
                unsigned int w0 = (unsigned int)f2bf(v.x) | ((unsigned int)f2bf(v.y) << 16);
                unsigned int w1 = (unsigned int)f2bf(v.z) | ((unsigned int)f2bf(v.w) << 16);
                *(unsigned int*)&Asb[r][ks + i * 4] = w0;
                *(unsigned int*)&Asb[r][ks + i * 4 + 2] = w1;
            }
        }
        {
            int kkp = t & 63;
            const float* Bp0 = B + (size_t)(k0 + kkp * 2) * Nout + n0 + w * 16;
            const float* Bp1 = Bp0 + Nout;
            #pragma unroll
            for (int j = 0; j < 16; j++) {
                unsigned int wv = (unsigned int)f2bf(Bp0[j]) | ((unsigned int)f2bf(Bp1[j]) << 16);
                *(unsigned int*)&Bsb[w * 16 + j][kkp * 2] = wv;
            }
        }
        __syncthreads();
        #pragma unroll
        for (int ksub = 0; ksub < 4; ksub++) {
            bf16x8 af = *(const bf16x8*)&Asb[w * 16 + lc][ksub * 32 + lg * 8];
            #pragma unroll
            for (int nsub = 0; nsub < 4; nsub++) {
                bf16x8 bfr = *(const bf16x8*)&Bsb[nsub * 16 + lc][ksub * 32 + lg * 8];
                acc[nsub] = __builtin_amdgcn_mfma_f32_16x16x32_bf16(af, bfr, acc[nsub], 0, 0, 0);
            }
        }
        __syncthreads();
    }
    float colsum[4], colsq[4];
    #pragma unroll
    for (int nsub = 0; nsub < 4; nsub++) {
        int cc = n0 + nsub * 16 + lc;
        float cs = 0.f, cq = 0.f;
        #pragma unroll
        for (int r = 0; r < 4; r++) {
            int m = m0 + w * 16 + lg * 4 + r;
            float v = acc[nsub][r];
            if (bias) v += bias[cc];
            if (res) v += res[(size_t)m * Nout + cc];
            if (relu) v = fmaxf(v, 0.f);
            C[(size_t)m * Nout + cc] = v;
            cs += v;
            cq = fmaf(v, v, cq);
        }
        colsum[nsub] = cs;
        colsq[nsub] = cq;
    }
    if (bnout) {
        __syncthreads();
        float* S1 = reinterpret_cast<float*>(&Asb[0][0]);
        float* S2 = S1 + 1024;
        #pragma unroll
        for (int nsub = 0; nsub < 4; nsub++) {
            S1[(nsub * 16 + lc) * 16 + w * 4 + lg] = colsum[nsub];
            S2[(nsub * 16 + lc) * 16 + w * 4 + lg] = colsq[nsub];
        }
        __syncthreads();
        if (t < 64) {
            float s = 0.f, q = 0.f;
            #pragma unroll
            for (int i = 0; i < 16; i++) { s += S1[t * 16 + i]; q += S2[t * 16 + i]; }
            atomicAdd(&bnout[n0 + t], s);
            atomicAdd(&bnout[128 + n0 + t], q);
        }
    }
}

// ---------------- fused 3-way input projection ----------------
__global__ __launch_bounds__(256) void proj3_kernel(
    const float* __restrict__ x_a, const float* __restrict__ Wa, const float* __restrict__ ba,
    const float* __restrict__ x_b, const float* __restrict__ Wb, const float* __restrict__ bb,
    const float* __restrict__ x_c, const float* __restrict__ Wc, const float* __restrict__ bc,
    float* __restrict__ h)
{
    __shared__ float As[128][64];
    __shared__ float Bs[128][64];
    int t = threadIdx.x;
    int tx = t & 15, ty = t >> 4;
    int by = blockIdx.y;
    const float* A; const float* B; const float* bias; int m0s, m0d;
    if (by < 32)      { A = x_a; B = Wa; bias = ba; m0s = by * 64;        m0d = m0s; }
    else if (by < 48) { A = x_b; B = Wb; bias = bb; m0s = (by - 32) * 64; m0d = 2048 + m0s; }
    else              { A = x_c; B = Wc; bias = bc; m0s = (by - 48) * 64; m0d = 3072 + m0s; }
    int n0 = blockIdx.x * 64;
    float acc[4][4] = {{0.f}};
    {
        int r = t & 63, kq = (t >> 6) << 2;
        const float* Ap = A + (size_t)(m0s + r) * 128 + kq;
        #pragma unroll
        for (int i = 0; i < 8; i++) {
            float4 v = *(const float4*)(Ap + i * 16);
            As[kq + i * 16 + 0][r] = v.x;
            As[kq + i * 16 + 1][r] = v.y;
            As[kq + i * 16 + 2][r] = v.z;
            As[kq + i * 16 + 3][r] = v.w;
        }
        int kk = t >> 4, c4 = (t & 15) << 2;
        #pragma unroll
        for (int i = 0; i < 8; i++) {
            float4 v = *(const float4*)(B + (size_t)(kk + i * 16) * 128 + n0 + c4);
            *(float4*)&Bs[kk + i * 16][c4] = v;
        }
    }
    __syncthreads();
    #pragma unroll 8
    for (int k = 0; k < 128; k++) {
        float4 a = *(const float4*)&As[k][ty << 2];
        float4 b = *(const float4*)&Bs[k][tx << 2];
        acc[0][0] = fmaf(a.x, b.x, acc[0][0]);
        acc[0][1] = fmaf(a.x, b.y, acc[0][1]);
        acc[0][2] = fmaf(a.x, b.z, acc[0][2]);
        acc[0][3] = fmaf(a.x, b.w, acc[0][3]);
        acc[1][0] = fmaf(a.y, b.x, acc[1][0]);
        acc[1][1] = fmaf(a.y, b.y, acc[1][1]);
        acc[1][2] = fmaf(a.y, b.z, acc[1][2]);
        acc[1][3] = fmaf(a.y, b.w, acc[1][3]);
        acc[2][0] = fmaf(a.z, b.x, acc[2][0]);
        acc[2][1] = fmaf(a.z, b.y, acc[2][1]);
        acc[2][2] = fmaf(a.z, b.z, acc[2][2]);
        acc[2][3] = fmaf(a.z, b.w, acc[2][3]);
        acc[3][0] = fmaf(a.w, b.x, acc[3][0]);
        acc[3][1] = fmaf(a.w, b.y, acc[3][1]);
        acc[3][2] = fmaf(a.w, b.z, acc[3][2]);
        acc[3][3] = fmaf(a.w, b.w, acc[3][3]);
    }
    #pragma unroll
    for (int i = 0; i < 4; i++) {
        int r = m0d + (ty << 2) + i;
        #pragma unroll
        for (int j = 0; j < 4; j++) {
            int cc = n0 + (tx << 2) + j;
            h[(size_t)r * 128 + cc] = acc[i][j] + bias[cc];
        }
    }
}

// ---------------- GAT attention scalar scores ----------------
__global__ __launch_bounds__(256) void att_scores(
    const float* __restrict__ xp, const float* __restrict__ att_src, const float* __restrict__ att_dst,
    float* __restrict__ asv, float* __restrict__ adv)
{
    int t = blockIdx.x * 256 + threadIdx.x;
    int n = t >> 2, hh = t & 3;
    const float* row = xp + (size_t)n * 128 + hh * 32;
    float s1 = 0.f, s2 = 0.f;
    #pragma unroll
    for (int c = 0; c < 32; c++) {
        float v = row[c];
        s1 = fmaf(v, att_src[hh * 32 + c], s1);
        s2 = fmaf(v, att_dst[hh * 32 + c], s2);
    }
    asv[t] = s1;
    adv[t] = s2;
}

// ---------------- CSR build ----------------
__global__ __launch_bounds__(256) void edge_hist(
    const int* __restrict__ ab_d, const int* __restrict__ ac_d, const int* __restrict__ cb_d,
    int* __restrict__ cnt)
{
    int e = blockIdx.x * 256 + threadIdx.x;
    int d;
    if (e < E_AB) d = ab_d[e] + NA;
    else if (e < E_AB + E_AC) d = ac_d[e - E_AB] + NA + NB;
    else if (e < E_HET) d = cb_d[e - E_AB - E_AC] + NA;
    else d = e - E_HET;
    atomicAdd(&cnt[d], 1);
}

__global__ __launch_bounds__(256) void scan_kernel(
    const int* __restrict__ cnt, int* __restrict__ rowptr, int* __restrict__ fill)
{
    __shared__ int sums[256];
    int t = threadIdx.x;
    int local[16];
    int s = 0;
    #pragma unroll
    for (int i = 0; i < 16; i++) { local[i] = s; s += cnt[t * 16 + i]; }
    sums[t] = s;
    __syncthreads();
    for (int d = 1; d < 256; d <<= 1) {
        int v = (t >= d) ? sums[t - d] : 0;
        __syncthreads();
        sums[t] += v;
        __syncthreads();
    }
    int base = sums[t] - s;
    #pragma unroll
    for (int i = 0; i < 16; i++) {
        int v = base + local[i];
        rowptr[t * 16 + i] = v;
        fill[t * 16 + i] = v;
    }
    if (t == 255) rowptr[NN] = sums[255];
}

__global__ __launch_bounds__(256) void edge_scatter(
    const int* __restrict__ ab_s, const int* __restrict__ ab_d,
    const int* __restrict__ ac_s, const int* __restrict__ ac_d,
    const int* __restrict__ cb_s, const int* __restrict__ cb_d,
    int* __restrict__ fill, int* __restrict__ csr)
{
    int e = blockIdx.x * 256 + threadIdx.x;
    int s, d;
    if (e < E_AB) { s = ab_s[e]; d = ab_d[e] + NA; }
    else if (e < E_AB + E_AC) { int i = e - E_AB; s = ac_s[i]; d = ac_d[i] + NA + NB; }
    else if (e < E_HET) { int i = e - E_AB - E_AC; s = cb_s[i] + NA + NB; d = cb_d[i] + NA; }
    else { s = e - E_HET; d = s; }
    int pos = atomicAdd(&fill[d], 1);
    csr[pos] = s;
}

// ---------------- GAT gather ----------------
__global__ __launch_bounds__(128) void gat_gather(
    const float* __restrict__ xp, const float* __restrict__ asv, const float* __restrict__ adv,
    const int* __restrict__ rowptr, const int* __restrict__ csr,
    const float* __restrict__ b_gat, const float* __restrict__ hres, float* __restrict__ y)
{
    __shared__ int sidx[GCHUNK];
    __shared__ float salpha[4][GCHUNK];
    int n = blockIdx.x;
    int t = threadIdx.x;
    int hh = t >> 5, lane = t & 31;
    int beg = rowptr[n], end = rowptr[n + 1];
    int deg = end - beg;
    float ad = adv[n * 4 + hh];
    float mh = -1e30f;
    for (int j = beg + lane; j < end; j += 32) {
        int s = csr[j];
        float e = asv[s * 4 + hh] + ad;
        e = (e > 0.f) ? e : 0.2f * e;
        mh = fmaxf(mh, e);
    }
    mh = fmaxf(mh, __shfl_xor(mh, 1));
    mh = fmaxf(mh, __shfl_xor(mh, 2));
    mh = fmaxf(mh, __shfl_xor(mh, 4));
    mh = fmaxf(mh, __shfl_xor(mh, 8));
    mh = fmaxf(mh, __shfl_xor(mh, 16));
    float dn = 0.f;
    for (int j = beg + lane; j < end; j += 32) {
        int s = csr[j];
        float e = asv[s * 4 + hh] + ad;
        e = (e > 0.f) ? e : 0.2f * e;
        dn += __expf(e - mh);
    }
    dn += __shfl_xor(dn, 1);
    dn += __shfl_xor(dn, 2);
    dn += __shfl_xor(dn, 4);
    dn += __shfl_xor(dn, 8);
    dn += __shfl_xor(dn, 16);
    float inv = 1.f / dn;
    float acc = 0.f;
    int c = lane;
    for (int c0 = 0; c0 < deg; c0 += GCHUNK) {
        int cn = min(GCHUNK, deg - c0);
        for (int jj = lane; jj < cn; jj += 32) {
            int s = csr[beg + c0 + jj];
            if (hh == 0) sidx[jj] = s;
            float e = asv[s * 4 + hh] + ad;
            e = (e > 0.f) ? e : 0.2f * e;
            salpha[hh][jj] = __expf(e - mh) * inv;
        }
        __syncthreads();
        #pragma unroll 4
        for (int j = 0; j < cn; j++) {
            acc = fmaf(salpha[hh][j], xp[(size_t)sidx[j] * 128 + hh * 32 + c], acc);
        }
        __syncthreads();
    }
    y[(size_t)n * 128 + t] = acc + b_gat[t] + hres[(size_t)n * 128 + t];
}

// ---------------- BatchNorm accumulate (for gat_gather output only) ----------------
__global__ __launch_bounds__(256) void bn_acc(
    const float* __restrict__ x, float* __restrict__ out)
{
    int t = threadIdx.x;
    int c = t & 127, rh = t >> 7;
    int r0 = blockIdx.x * 128;   // grid 32
    float s = 0.f, s2 = 0.f;
    for (int r = rh; r < 128; r += 2) {
        float v = x[(size_t)(r0 + r) * 128 + c];
        s += v;
        s2 = fmaf(v, v, s2);
    }
    __shared__ float bs[256], bq[256];
    bs[t] = s; bq[t] = s2;
    __syncthreads();
    if (t < 128) {
        atomicAdd(&out[c], bs[t] + bs[t + 128]);
        atomicAdd(&out[128 + c], bq[t] + bq[t + 128]);
    }
}

// ---------------- MFMA flash attention (online-max, KSLICES=4; R23-proven) ----------------
// 256-thread blocks = 4 independent waves; wave w owns q-rows (qb*4+w)*16.
// grid ksl(4) x h(4) x qb(64) = 1024 blocks.
__global__ __launch_bounds__(256) void attn_kernel(
    const unsigned short* __restrict__ Qb, const unsigned short* __restrict__ Kb,
    const unsigned short* __restrict__ Vt, float* __restrict__ po,
    float* __restrict__ pm, float* __restrict__ pl)
{
    __shared__ unsigned short P16[4][16][72];
    int bid = blockIdx.x;
    int ksl = bid & 3;
    int h = (bid >> 2) & 3;
    int qb = bid >> 4;
    int t = threadIdx.x;
    int w = t >> 6;
    int l = t & 63;
    int lg = l >> 4, lc = l & 15;
    int q0 = (qb * 4 + w) * 16;
    f32x4 zero = {0.f, 0.f, 0.f, 0.f};
    const unsigned short* Qh = Qb + h * 131072;
    const unsigned short* Kh = Kb + h * 131072;
    const unsigned short* Vh = Vt + h * 131072;
    bf16x8 qf = *(const bf16x8*)(Qh + (size_t)(q0 + lc) * 32 + lg * 8);
    f32x4 o0 = zero, o1 = zero;
    float mx[4] = {-1e30f, -1e30f, -1e30f, -1e30f};
    float ls[4] = {0.f, 0.f, 0.f, 0.f};
    int kbeg = ksl * KSLEN;
    #pragma unroll 1
    for (int kt = kbeg; kt < kbeg + KSLEN; kt += 64) {
        f32x4 s[4];
        #pragma unroll
        for (int sub = 0; sub < 4; sub++) {
            bf16x8 kf = *(const bf16x8*)(Kh + (size_t)(kt + sub * 16 + lc) * 32 + lg * 8);
            s[sub] = __builtin_amdgcn_mfma_f32_16x16x32_bf16(qf, kf, zero, 0, 0, 0);
        }
        bf16x8 vf[2][2];
        #pragma unroll
        for (int ks = 0; ks < 2; ks++)
            #pragma unroll
            for (int ct = 0; ct < 2; ct++)
                vf[ks][ct] = *(const bf16x8*)(Vh + (size_t)(ct * 16 + lc) * 4096 + kt + ks * 32 + lg * 8);
        float p_[4][4];
        #pragma unroll
        for (int r = 0; r < 4; r++) {
            float tm = fmaxf(fmaxf(s[0][r], s[1][r]), fmaxf(s[2][r], s[3][r]));
            tm = fmaxf(tm, __shfl_xor(tm, 1));
            tm = fmaxf(tm, __shfl_xor(tm, 2));
            tm = fmaxf(tm, __shfl_xor(tm, 4));
            tm = fmaxf(tm, __shfl_xor(tm, 8));
            if (tm > mx[r]) {
                float cr = __expf(mx[r] - tm);
                ls[r] *= cr;
                o0[r] *= cr;
                o1[r] *= cr;
                mx[r] = tm;
            }
            float rs = 0.f;
            #pragma unroll
            for (int sub = 0; sub < 4; sub++) {
                p_[sub][r] = __expf(s[sub][r] - mx[r]);
                rs += p_[sub][r];
            }
            rs += __shfl_xor(rs, 1);
            rs += __shfl_xor(rs, 2);
            rs += __shfl_xor(rs, 4);
            rs += __shfl_xor(rs, 8);
            ls[r] += rs;
        }
        #pragma unroll
        for (int sub = 0; sub < 4; sub++)
            #pragma unroll
            for (int r = 0; r < 4; r++)
                P16[w][lg * 4 + r][sub * 16 + lc] = f2bf(p_[sub][r]);
        bf16x8 pa[2];
        #pragma unroll
        for (int ks = 0; ks < 2; ks++)
            pa[ks] = *(const bf16x8*)(&P16[w][lc][ks * 32 + lg * 8]);
        #pragma unroll
        for (int ks = 0; ks < 2; ks++) {
            o0 = __builtin_amdgcn_mfma_f32_16x16x32_bf16(pa[ks], vf[ks][0], o0, 0, 0, 0);
            o1 = __builtin_amdgcn_mfma_f32_16x16x32_bf16(pa[ks], vf[ks][1], o1, 0, 0, 0);
        }
    }
    int base0 = (ksl * HHH + h) * NN + q0;
    #pragma unroll
    for (int r = 0; r < 4; r++) {
        size_t ob = (size_t)(base0 + lg * 4 + r) * 32;
        po[ob + lc] = o0[r];
        po[ob + 16 + lc] = o1[r];
    }
    #pragma unroll
    for (int r = 0; r < 4; r++) {
        if (lc == r) {
            pm[base0 + lg * 4 + r] = mx[r];
            pl[base0 + lg * 4 + r] = ls[r];
        }
    }
}

__global__ __launch_bounds__(256) void attn_comb(
    const float* __restrict__ po, const float* __restrict__ pm, const float* __restrict__ pl,
    float* __restrict__ o_at)
{
    int idx = blockIdx.x * 256 + threadIdx.x;  // N*128
    int n = idx >> 7, hc = idx & 127, hh = hc >> 5, c = idx & 31;
    float M = -1e30f;
    #pragma unroll
    for (int s = 0; s < KSLICES; s++) M = fmaxf(M, pm[(s * HHH + hh) * NN + n]);
    float accv = 0.f, L = 0.f;
    #pragma unroll
    for (int s = 0; s < KSLICES; s++) {
        int id = (s * HHH + hh) * NN + n;
        float wgt = __expf(pm[id] - M);
        L = fmaf(wgt, pl[id], L);
        accv = fmaf(wgt, po[(size_t)id * 32 + c], accv);
    }
    o_at[idx] = accv / L;
}

// ---------------- combine; final (BN from raw sums) ----------------
__global__ __launch_bounds__(256) void combine_kernel(
    const float* __restrict__ y1, const float* __restrict__ y2,
    const float* __restrict__ stats,
    const float* __restrict__ g1, const float* __restrict__ be1,
    const float* __restrict__ g2, const float* __restrict__ be2,
    float* __restrict__ outp)
{
    int idx = blockIdx.x * 256 + threadIdx.x;
    int c = idx & 127;
    const float invn = 1.f / (float)NN;
    float mu1 = stats[c] * invn;
    float r1 = rsqrtf(stats[128 + c] * invn - mu1 * mu1 + EPSV);
    float mu2 = stats[256 + c] * invn;
    float r2 = rsqrtf(stats[384 + c] * invn - mu2 * mu2 + EPSV);
    float v1 = (y1[idx] - mu1) * r1 * g1[c] + be1[c];
    float v2 = (y2[idx] - mu2) * r2 * g2[c] + be2[c];
    outp[idx] = v1 + v2;
}

__global__ __launch_bounds__(256) void final_kernel(
    const float* __restrict__ out2, const float* __restrict__ stats,
    const float* __restrict__ g3, const float* __restrict__ be3,
    float* __restrict__ outv)
{
    int idx = blockIdx.x * 256 + threadIdx.x;
    int c = idx & 127;
    const float invn = 1.f / (float)NN;
    float mu = stats[512 + c] * invn;
    float r = rsqrtf(stats[640 + c] * invn - mu * mu + EPSV);
    outv[idx] = (out2[idx] - mu) * r * g3[c] + be3[c];
}

extern "C" void kernel_launch(void* const* d_in, const int* in_sizes, int n_in,
                              void* d_out, int out_size, void* d_ws, size_t ws_size,
                              hipStream_t stream)
{
    (void)in_sizes; (void)n_in; (void)out_size; (void)ws_size;
    const float* x_a   = (const float*)d_in[0];
    const float* x_b   = (const float*)d_in[1];
    const float* x_c   = (const float*)d_in[2];
    const int* ab_s    = (const int*)d_in[3];
    const int* ab_d    = (const int*)d_in[4];
    const int* ac_s    = (const int*)d_in[5];
    const int* ac_d    = (const int*)d_in[6];
    const int* cb_s    = (const int*)d_in[7];
    const int* cb_d    = (const int*)d_in[8];
    const float* W_in_a = (const float*)d_in[9];
    const float* b_in_a = (const float*)d_in[10];
    const float* W_in_b = (const float*)d_in[11];
    const float* b_in_b = (const float*)d_in[12];
    const float* W_in_c = (const float*)d_in[13];
    const float* b_in_c = (const float*)d_in[14];
    const float* W_gat  = (const float*)d_in[15];
    const float* att_src = (const float*)d_in[16];
    const float* att_dst = (const float*)d_in[17];
    const float* b_gat  = (const float*)d_in[18];
    const float* W_qkv  = (const float*)d_in[19];
    const float* b_qkv  = (const float*)d_in[20];
    const float* W_o    = (const float*)d_in[21];
    const float* b_o    = (const float*)d_in[22];
    const float* g1     = (const float*)d_in[23];
    const float* be1    = (const float*)d_in[24];
    const float* g2     = (const float*)d_in[25];
    const float* be2    = (const float*)d_in[26];
    const float* g3     = (const float*)d_in[27];
    const float* be3    = (const float*)d_in[28];
    const float* W_mlp1 = (const float*)d_in[29];
    const float* b_mlp1 = (const float*)d_in[30];
    const float* W_mlp2 = (const float*)d_in[31];
    const float* b_mlp2 = (const float*)d_in[32];

    float* ws   = (float*)d_ws;
    float* h    = ws + 0;          // 524288
    float* o_at = ws + 2097152;    // 524288
    float* y2   = ws + 2621440;    // 524288 (attn-time: pm/pl; later: o-proj+res)
    float* stats = ws + 3145728;   // 768 (raw sums; zeroed each launch)
    float* R    = ws + 3146496;    // reused region
    // attention-time views:
    float* po = R;                        // 4*4*4096*32 = 2097152 floats
    unsigned short* Qb = (unsigned short*)(R + 2097152);  // 262144 bf16
    unsigned short* Kb = (unsigned short*)(R + 2228224);
    unsigned short* Vt = (unsigned short*)(R + 2359296);
    float* pm = y2;                // 65536
    float* pl = y2 + 65536;        // 65536
    // post-attention view of R:
    float* xp   = R + 0;           // 524288
    float* y1   = R + 524288;      // 524288
    float* outp = R + 1048576;     // 524288
    float* hid  = R + 1572864;     // 1048576
    float* out2 = R + 2621440;     // 524288
    float* asv  = R + 3145728;     // 16384
    float* adv  = R + 3162112;     // 16384
    int* cnt    = (int*)(R + 3178496);
    int* rowptr = cnt + 4096;      // 4104 incl pad
    int* fill   = rowptr + 4104;
    int* csr    = fill + 4096;     // E_TOT

    hipMemsetAsync(stats, 0, 768 * sizeof(float), stream);

    // ---- fused input projections + qkv (qkv GEMM packs bf16 Q/K/V directly) ----
    proj3_kernel<<<dim3(2, 64), 256, 0, stream>>>(x_a, W_in_a, b_in_a, x_b, W_in_b, b_in_b, x_c, W_in_c, b_in_c, h);
    gemm_kernel<<<dim3(6, 64), 256, 0, stream>>>(h, W_qkv, b_qkv, nullptr, nullptr, NN, 384, 128, 1, 0, nullptr, Qb, Kb, Vt);
    // ---- global attention (MFMA flash, online-max) ----
    attn_kernel<<<64 * HHH * KSLICES, 256, 0, stream>>>(Qb, Kb, Vt, po, pm, pl);
    attn_comb<<<NN * 128 / 256, 256, 0, stream>>>(po, pm, pl, o_at);
    gemm_kernel<<<dim3(2, 64), 256, 0, stream>>>(o_at, W_o, b_o, h, y2, NN, 128, 128, 1, 0, stats + 256, nullptr, nullptr, nullptr);
    // ---- GAT branch (R reused; W_gat projection via MFMA bf16) ----
    mgemm_kernel<<<dim3(2, 64), 256, 0, stream>>>(h, W_gat, nullptr, nullptr, xp, NN, 128, 128, 0, nullptr);
    att_scores<<<64, 256, 0, stream>>>(xp, att_src, att_dst, asv, adv);
    hipMemsetAsync(cnt, 0, NN * sizeof(int), stream);
    edge_hist<<<E_TOT / 256, 256, 0, stream>>>(ab_d, ac_d, cb_d, cnt);
    scan_kernel<<<1, 256, 0, stream>>>(cnt, rowptr, fill);
    edge_scatter<<<E_TOT / 256, 256, 0, stream>>>(ab_s, ab_d, ac_s, ac_d, cb_s, cb_d, fill, csr);
    gat_gather<<<NN, 128, 0, stream>>>(xp, asv, adv, rowptr, csr, b_gat, h, y1);
    bn_acc<<<32, 256, 0, stream>>>(y1, stats + 0);
    // ---- combine + MLP (MFMA bf16 GEMMs) ----
    combine_kernel<<<NN * 128 / 256, 256, 0, stream>>>(y1, y2, stats, g1, be1, g2, be2, outp);
    mgemm_kernel<<<dim3(4, 64), 256, 0, stream>>>(outp, W_mlp1, b_mlp1, nullptr, hid, NN, 256, 128, 1, nullptr);
    mgemm_kernel<<<dim3(2, 64), 256, 0, stream>>>(hid, W_mlp2, b_mlp2, outp, out2, NN, 128, 256, 0, stats + 512);
    final_kernel<<<NN * 128 / 256, 256, 0, stream>>>(out2, stats, g3, be3, (float*)d_out);
}

// Round 26
// 218.624 us; speedup vs baseline: 1.0282x; 1.0058x over previous
//
#include <hip/hip_runtime.h>
#include <math.h>

#define NA 2048
#define NB 1024
#define NC 1024
#define NN 4096
#define DD 128
#define HHH 4
#define CCC 32
#define E_AB 65536
#define E_AC 32768
#define E_CB 32768
#define E_HET 131072
#define E_TOT 135168
#define EPSV 1e-5f
#define SCALEV 0.17677669529663687f
#define KSLICES 4
#define KSLEN 1024
#define GCHUNK 256

typedef __attribute__((ext_vector_type(8))) short bf16x8;
typedef __attribute__((ext_vector_type(4))) float f32x4;

static __device__ __forceinline__ unsigned short f2bf(float x) {
    union { float f; unsigned int u; } v; v.f = x;
    unsigned int r = v.u + 0x7FFF + ((v.u >> 16) & 1);
    return (unsigned short)(r >> 16);
}

// ---------------- generic tiled GEMM + optional bf16-pack epilogue + optional BN accumulate ----
__global__ __launch_bounds__(256) void gemm_kernel(
    const float* __restrict__ A, const float* __restrict__ B,
    const float* __restrict__ bias, const float* __restrict__ res,
    float* __restrict__ C, int M, int Nout, int K, int transB, int relu,
    float* __restrict__ bnout,
    unsigned short* __restrict__ Qb, unsigned short* __restrict__ Kb,
    unsigned short* __restrict__ Vt)
{
    __shared__ float As[128][64];
    __shared__ float Bs[128][64];
    int t = threadIdx.x;
    int tx = t & 15, ty = t >> 4;
    int m0 = blockIdx.y * 64, n0 = blockIdx.x * 64;
    float acc[4][4] = {{0.f}};
    for (int k0 = 0; k0 < K; k0 += 128) {
        {
            int r = t & 63, kq = (t >> 6) << 2;
            const float* Ap = A + (size_t)(m0 + r) * K + k0 + kq;
            #pragma unroll
            for (int i = 0; i < 8; i++) {
                float4 v = *(const float4*)(Ap + i * 16);
                As[kq + i * 16 + 0][r] = v.x;
                As[kq + i * 16 + 1][r] = v.y;
                As[kq + i * 16 + 2][r] = v.z;
                As[kq + i * 16 + 3][r] = v.w;
            }
        }
        if (!transB) {
            int kk = t >> 4, c4 = (t & 15) << 2;
            #pragma unroll
            for (int i = 0; i < 8; i++) {
                float4 v = *(const float4*)(B + (size_t)(k0 + kk + i * 16) * Nout + n0 + c4);
                *(float4*)&Bs[kk + i * 16][c4] = v;
            }
        } else {
            int c = t & 63, kq = (t >> 6) << 2;
            const float* Bp = B + (size_t)(n0 + c) * K + k0 + kq;
            #pragma unroll
            for (int i = 0; i < 8; i++) {
                float4 v = *(const float4*)(Bp + i * 16);
                Bs[kq + i * 16 + 0][c] = v.x;
                Bs[kq + i * 16 + 1][c] = v.y;
                Bs[kq + i * 16 + 2][c] = v.z;
                Bs[kq + i * 16 + 3][c] = v.w;
            }
        }
        __syncthreads();
        #pragma unroll 8
        for (int k = 0; k < 128; k++) {
            float4 a = *(const float4*)&As[k][ty << 2];
            float4 b = *(const float4*)&Bs[k][tx << 2];
            acc[0][0] = fmaf(a.x, b.x, acc[0][0]);
            acc[0][1] = fmaf(a.x, b.y, acc[0][1]);
            acc[0][2] = fmaf(a.x, b.z, acc[0][2]);
            acc[0][3] = fmaf(a.x, b.w, acc[0][3]);
            acc[1][0] = fmaf(a.y, b.x, acc[1][0]);
            acc[1][1] = fmaf(a.y, b.y, acc[1][1]);
            acc[1][2] = fmaf(a.y, b.z, acc[1][2]);
            acc[1][3] = fmaf(a.y, b.w, acc[1][3]);
            acc[2][0] = fmaf(a.z, b.x, acc[2][0]);
            acc[2][1] = fmaf(a.z, b.y, acc[2][1]);
            acc[2][2] = fmaf(a.z, b.z, acc[2][2]);
            acc[2][3] = fmaf(a.z, b.w, acc[2][3]);
            acc[3][0] = fmaf(a.w, b.x, acc[3][0]);
            acc[3][1] = fmaf(a.w, b.y, acc[3][1]);
            acc[3][2] = fmaf(a.w, b.z, acc[3][2]);
            acc[3][3] = fmaf(a.w, b.w, acc[3][3]);
        }
        __syncthreads();
    }
    if (Qb) {
        #pragma unroll
        for (int i = 0; i < 4; i++) {
            int r = m0 + (ty << 2) + i;
            #pragma unroll
            for (int j = 0; j < 4; j++) {
                int cc = n0 + (tx << 2) + j;
                float v = acc[i][j] + bias[cc];
                if (cc < 128) {
                    Qb[(cc >> 5) * 131072 + r * 32 + (cc & 31)] = f2bf(v * SCALEV);
                } else if (cc < 256) {
                    int d = cc - 128;
                    Kb[(d >> 5) * 131072 + r * 32 + (d & 31)] = f2bf(v);
                } else {
                    int d = cc - 256;
                    Vt[(d >> 5) * 131072 + (d & 31) * 4096 + r] = f2bf(v);
                }
            }
        }
        return;
    }
    float colsum[4] = {0.f, 0.f, 0.f, 0.f};
    float colsq[4] = {0.f, 0.f, 0.f, 0.f};
    #pragma unroll
    for (int i = 0; i < 4; i++) {
        int r = m0 + (ty << 2) + i;
        #pragma unroll
        for (int j = 0; j < 4; j++) {
            int cc = n0 + (tx << 2) + j;
            float v = acc[i][j];
            if (bias) v += bias[cc];
            if (res) v += res[(size_t)r * Nout + cc];
            if (relu) v = fmaxf(v, 0.f);
            C[(size_t)r * Nout + cc] = v;
            colsum[j] += v;
            colsq[j] = fmaf(v, v, colsq[j]);
        }
    }
    if (bnout) {
        __syncthreads();
        #pragma unroll
        for (int j = 0; j < 4; j++) {
            As[(tx << 2) + j][ty] = colsum[j];
            Bs[(tx << 2) + j][ty] = colsq[j];
        }
        __syncthreads();
        if (t < 64) {
            float s = 0.f, q = 0.f;
            #pragma unroll
            for (int k = 0; k < 16; k++) { s += As[t][k]; q += Bs[t][k]; }
            atomicAdd(&bnout[n0 + t], s);
            atomicAdd(&bnout[128 + n0 + t], q);
        }
    }
}

// ---------------- MFMA bf16 GEMM (+bias,+res,relu,bn; +optional fused GAT att-scores) ------
// If asv != nullptr (W_gat call: no bias/res/relu): each block owns 2 complete heads of
// every row it computes; per-head dot products with atts/attd reduced across the 16-lane
// group and written to asv/adv. Arithmetic uses the same acc values written to C.
__global__ __launch_bounds__(256) void mgemm_kernel(
    const float* __restrict__ A, const float* __restrict__ B,
    const float* __restrict__ bias, const float* __restrict__ res,
    float* __restrict__ C, int M, int Nout, int K, int relu,
    float* __restrict__ bnout,
    const float* __restrict__ atts, const float* __restrict__ attd,
    float* __restrict__ asv, float* __restrict__ adv)
{
    __shared__ unsigned short Asb[64][136];
    __shared__ unsigned short Bsb[64][136];
    int t = threadIdx.x;
    int w = t >> 6, l = t & 63, lg = l >> 4, lc = l & 15;
    int m0 = blockIdx.y * 64, n0 = blockIdx.x * 64;
    f32x4 zero = {0.f, 0.f, 0.f, 0.f};
    f32x4 acc[4] = {zero, zero, zero, zero};
    for (int k0 = 0; k0 < K; k0 += 128) {
        {
            int r = t & 63, ks = w * 32;
            const float* Ap = A + (size_t)(m0 + r) * K + k0 + ks;
            #pragma unroll
            for (int i = 0; i < 8; i++) {
                float4 v = *(const float4*)(Ap + i * 4);
                unsigned int w0 = (unsigned int)f2bf(v.x) | ((unsigned int)f2bf(v.y) << 16);
                unsigned int w1 = (unsigned int)f2bf(v.z) | ((unsigned int)f2bf(v.w) << 16);
                *(unsigned int*)&Asb[r][ks + i * 4] = w0;
                *(unsigned int*)&Asb[r][ks + i * 4 + 2] = w1;
            }
        }
        {
            int kkp = t & 63;
            const float* Bp0 = B + (size_t)(k0 + kkp * 2) * Nout + n0 + w * 16;
            const float* Bp1 = Bp0 + Nout;
            #pragma unroll
            for (int j = 0; j < 16; j++) {
                unsigned int wv = (unsigned int)f2bf(Bp0[j]) | ((unsigned int)f2bf(Bp1[j]) << 16);
                *(unsigned int*)&Bsb[w * 16 + j][kkp * 2] = wv;
            }
        }
        __syncthreads();
        #pragma unroll
        for (int ksub = 0; ksub < 4; ksub++) {
            bf16x8 af = *(const bf16x8*)&Asb[w * 16 + lc][ksub * 32 + lg * 8];
            #pragma unroll
            for (int nsub = 0; nsub < 4; nsub++) {
                bf16x8 bfr = *(const bf16x8*)&Bsb[nsub * 16 + lc][ksub * 32 + lg * 8];
                acc[nsub] = __builtin_amdgcn_mfma_f32_16x16x32_bf16(af, bfr, acc[nsub], 0, 0, 0);
            }
        }
        __syncthreads();
    }
    float colsum[4], colsq[4];
    #pragma unroll
    for (int nsub = 0; nsub < 4; nsub++) {
        int cc = n0 + nsub * 16 + lc;
        float cs = 0.f, cq = 0.f;
        #pragma unroll
        for (int r = 0; r < 4; r++) {
            int m = m0 + w * 16 + lg * 4 + r;
            float v = acc[nsub][r];
            if (bias) v += bias[cc];
            if (res) v += res[(size_t)m * Nout + cc];
            if (relu) v = fmaxf(v, 0.f);
            C[(size_t)m * Nout + cc] = v;
            cs += v;
            cq = fmaf(v, v, cq);
        }
        colsum[nsub] = cs;
        colsq[nsub] = cq;
    }
    if (asv) {
        // fused GAT att-scores: heads (n0>>5) and (n0>>5)+1 fully owned by this block
        #pragma unroll
        for (int hp = 0; hp < 2; hp++) {
            int head = (n0 >> 5) + hp;
            float a0 = atts[head * 32 + lc], a1 = atts[head * 32 + 16 + lc];
            float d0 = attd[head * 32 + lc], d1 = attd[head * 32 + 16 + lc];
            #pragma unroll
            for (int r = 0; r < 4; r++) {
                float v1 = fmaf(acc[2 * hp][r], a0, acc[2 * hp + 1][r] * a1);
                float v2 = fmaf(acc[2 * hp][r], d0, acc[2 * hp + 1][r] * d1);
                v1 += __shfl_xor(v1, 1); v2 += __shfl_xor(v2, 1);
                v1 += __shfl_xor(v1, 2); v2 += __shfl_xor(v2, 2);
                v1 += __shfl_xor(v1, 4); v2 += __shfl_xor(v2, 4);
                v1 += __shfl_xor(v1, 8); v2 += __shfl_xor(v2, 8);
                if (lc == 0) {
                    int m = m0 + w * 16 + lg * 4 + r;
                    asv[m * 4 + head] = v1;
                    adv[m * 4 + head] = v2;
                }
            }
        }
    }
    if (bnout) {
        __syncthreads();
        float* S1 = reinterpret_cast<float*>(&Asb[0][0]);
        float* S2 = S1 + 1024;
        #pragma unroll
        for (int nsub = 0; nsub < 4; nsub++) {
            S1[(nsub * 16 + lc) * 16 + w * 4 + lg] = colsum[nsub];
            S2[(nsub * 16 + lc) * 16 + w * 4 + lg] = colsq[nsub];
        }
        __syncthreads();
        if (t < 64) {
            float s = 0.f, q = 0.f;
            #pragma unroll
            for (int i = 0; i < 16; i++) { s += S1[t * 16 + i]; q += S2[t * 16 + i]; }
            atomicAdd(&bnout[n0 + t], s);
            atomicAdd(&bnout[128 + n0 + t], q);
        }
    }
}

// ---------------- fused 3-way input projection ----------------
__global__ __launch_bounds__(256) void proj3_kernel(
    const float* __restrict__ x_a, const float* __restrict__ Wa, const float* __restrict__ ba,
    const float* __restrict__ x_b, const float* __restrict__ Wb, const float* __restrict__ bb,
    const float* __restrict__ x_c, const float* __restrict__ Wc, const float* __restrict__ bc,
    float* __restrict__ h)
{
    __shared__ float As[128][64];
    __shared__ float Bs[128][64];
    int t = threadIdx.x;
    int tx = t & 15, ty = t >> 4;
    int by = blockIdx.y;
    const float* A; const float* B; const float* bias; int m0s, m0d;
    if (by < 32)      { A = x_a; B = Wa; bias = ba; m0s = by * 64;        m0d = m0s; }
    else if (by < 48) { A = x_b; B = Wb; bias = bb; m0s = (by - 32) * 64; m0d = 2048 + m0s; }
    else              { A = x_c; B = Wc; bias = bc; m0s = (by - 48) * 64; m0d = 3072 + m0s; }
    int n0 = blockIdx.x * 64;
    float acc[4][4] = {{0.f}};
    {
        int r = t & 63, kq = (t >> 6) << 2;
        const float* Ap = A + (size_t)(m0s + r) * 128 + kq;
        #pragma unroll
        for (int i = 0; i < 8; i++) {
            float4 v = *(const float4*)(Ap + i * 16);
            As[kq + i * 16 + 0][r] = v.x;
            As[kq + i * 16 + 1][r] = v.y;
            As[kq + i * 16 + 2][r] = v.z;
            As[kq + i * 16 + 3][r] = v.w;
        }
        int kk = t >> 4, c4 = (t & 15) << 2;
        #pragma unroll
        for (int i = 0; i < 8; i++) {
            float4 v = *(const float4*)(B + (size_t)(kk + i * 16) * 128 + n0 + c4);
            *(float4*)&Bs[kk + i * 16][c4] = v;
        }
    }
    __syncthreads();
    #pragma unroll 8
    for (int k = 0; k < 128; k++) {
        float4 a = *(const float4*)&As[k][ty << 2];
        float4 b = *(const float4*)&Bs[k][tx << 2];
        acc[0][0] = fmaf(a.x, b.x, acc[0][0]);
        acc[0][1] = fmaf(a.x, b.y, acc[0][1]);
        acc[0][2] = fmaf(a.x, b.z, acc[0][2]);
        acc[0][3] = fmaf(a.x, b.w, acc[0][3]);
        acc[1][0] = fmaf(a.y, b.x, acc[1][0]);
        acc[1][1] = fmaf(a.y, b.y, acc[1][1]);
        acc[1][2] = fmaf(a.y, b.z, acc[1][2]);
        acc[1][3] = fmaf(a.y, b.w, acc[1][3]);
        acc[2][0] = fmaf(a.z, b.x, acc[2][0]);
        acc[2][1] = fmaf(a.z, b.y, acc[2][1]);
        acc[2][2] = fmaf(a.z, b.z, acc[2][2]);
        acc[2][3] = fmaf(a.z, b.w, acc[2][3]);
        acc[3][0] = fmaf(a.w, b.x, acc[3][0]);
        acc[3][1] = fmaf(a.w, b.y, acc[3][1]);
        acc[3][2] = fmaf(a.w, b.z, acc[3][2]);
        acc[3][3] = fmaf(a.w, b.w, acc[3][3]);
    }
    #pragma unroll
    for (int i = 0; i < 4; i++) {
        int r = m0d + (ty << 2) + i;
        #pragma unroll
        for (int j = 0; j < 4; j++) {
            int cc = n0 + (tx << 2) + j;
            h[(size_t)r * 128 + cc] = acc[i][j] + bias[cc];
        }
    }
}

// ---------------- CSR build ----------------
__global__ __launch_bounds__(256) void edge_hist(
    const int* __restrict__ ab_d, const int* __restrict__ ac_d, const int* __restrict__ cb_d,
    int* __restrict__ cnt)
{
    int e = blockIdx.x * 256 + threadIdx.x;
    int d;
    if (e < E_AB) d = ab_d[e] + NA;
    else if (e < E_AB + E_AC) d = ac_d[e - E_AB] + NA + NB;
    else if (e < E_HET) d = cb_d[e - E_AB - E_AC] + NA;
    else d = e - E_HET;
    atomicAdd(&cnt[d], 1);
}

__global__ __launch_bounds__(256) void scan_kernel(
    const int* __restrict__ cnt, int* __restrict__ rowptr, int* __restrict__ fill)
{
    __shared__ int sums[256];
    int t = threadIdx.x;
    int local[16];
    int s = 0;
    #pragma unroll
    for (int i = 0; i < 16; i++) { local[i] = s; s += cnt[t * 16 + i]; }
    sums[t] = s;
    __syncthreads();
    for (int d = 1; d < 256; d <<= 1) {
        int v = (t >= d) ? sums[t - d] : 0;
        __syncthreads();
        sums[t] += v;
        __syncthreads();
    }
    int base = sums[t] - s;
    #pragma unroll
    for (int i = 0; i < 16; i++) {
        int v = base + local[i];
        rowptr[t * 16 + i] = v;
        fill[t * 16 + i] = v;
    }
    if (t == 255) rowptr[NN] = sums[255];
}

__global__ __launch_bounds__(256) void edge_scatter(
    const int* __restrict__ ab_s, const int* __restrict__ ab_d,
    const int* __restrict__ ac_s, const int* __restrict__ ac_d,
    const int* __restrict__ cb_s, const int* __restrict__ cb_d,
    int* __restrict__ fill, int* __restrict__ csr)
{
    int e = blockIdx.x * 256 + threadIdx.x;
    int s, d;
    if (e < E_AB) { s = ab_s[e]; d = ab_d[e] + NA; }
    else if (e < E_AB + E_AC) { int i = e - E_AB; s = ac_s[i]; d = ac_d[i] + NA + NB; }
    else if (e < E_HET) { int i = e - E_AB - E_AC; s = cb_s[i] + NA + NB; d = cb_d[i] + NA; }
    else { s = e - E_HET; d = s; }
    int pos = atomicAdd(&fill[d], 1);
    csr[pos] = s;
}

// ---------------- GAT gather ----------------
__global__ __launch_bounds__(128) void gat_gather(
    const float* __restrict__ xp, const float* __restrict__ asv, const float* __restrict__ adv,
    const int* __restrict__ rowptr, const int* __restrict__ csr,
    const float* __restrict__ b_gat, const float* __restrict__ hres, float* __restrict__ y)
{
    __shared__ int sidx[GCHUNK];
    __shared__ float salpha[4][GCHUNK];
    int n = blockIdx.x;
    int t = threadIdx.x;
    int hh = t >> 5, lane = t & 31;
    int beg = rowptr[n], end = rowptr[n + 1];
    int deg = end - beg;
    float ad = adv[n * 4 + hh];
    float mh = -1e30f;
    for (int j = beg + lane; j < end; j += 32) {
        int s = csr[j];
        float e = asv[s * 4 + hh] + ad;
        e = (e > 0.f) ? e : 0.2f * e;
        mh = fmaxf(mh, e);
    }
    mh = fmaxf(mh, __shfl_xor(mh, 1));
    mh = fmaxf(mh, __shfl_xor(mh, 2));
    mh = fmaxf(mh, __shfl_xor(mh, 4));
    mh = fmaxf(mh, __shfl_xor(mh, 8));
    mh = fmaxf(mh, __shfl_xor(mh, 16));
    float dn = 0.f;
    for (int j = beg + lane; j < end; j += 32) {
        int s = csr[j];
        float e = asv[s * 4 + hh] + ad;
        e = (e > 0.f) ? e : 0.2f * e;
        dn += __expf(e - mh);
    }
    dn += __shfl_xor(dn, 1);
    dn += __shfl_xor(dn, 2);
    dn += __shfl_xor(dn, 4);
    dn += __shfl_xor(dn, 8);
    dn += __shfl_xor(dn, 16);
    float inv = 1.f / dn;
    float acc = 0.f;
    int c = lane;
    for (int c0 = 0; c0 < deg; c0 += GCHUNK) {
        int cn = min(GCHUNK, deg - c0);
        for (int jj = lane; jj < cn; jj += 32) {
            int s = csr[beg + c0 + jj];
            if (hh == 0) sidx[jj] = s;
            float e = asv[s * 4 + hh] + ad;
            e = (e > 0.f) ? e : 0.2f * e;
            salpha[hh][jj] = __expf(e - mh) * inv;
        }
        __syncthreads();
        #pragma unroll 4
        for (int j = 0; j < cn; j++) {
            acc = fmaf(salpha[hh][j], xp[(size_t)sidx[j] * 128 + hh * 32 + c], acc);
        }
        __syncthreads();
    }
    y[(size_t)n * 128 + t] = acc + b_gat[t] + hres[(size_t)n * 128 + t];
}

// ---------------- BatchNorm accumulate (for gat_gather output only) ----------------
__global__ __launch_bounds__(256) void bn_acc(
    const float* __restrict__ x, float* __restrict__ out)
{
    int t = threadIdx.x;
    int c = t & 127, rh = t >> 7;
    int r0 = blockIdx.x * 128;   // grid 32
    float s = 0.f, s2 = 0.f;
    for (int r = rh; r < 128; r += 2) {
        float v = x[(size_t)(r0 + r) * 128 + c];
        s += v;
        s2 = fmaf(v, v, s2);
    }
    __shared__ float bs[256], bq[256];
    bs[t] = s; bq[t] = s2;
    __syncthreads();
    if (t < 128) {
        atomicAdd(&out[c], bs[t] + bs[t + 128]);
        atomicAdd(&out[128 + c], bq[t] + bq[t + 128]);
    }
}

// ---------------- MFMA flash attention (online-max, KSLICES=4; R23-proven) ----------------
__global__ __launch_bounds__(256) void attn_kernel(
    const unsigned short* __restrict__ Qb, const unsigned short* __restrict__ Kb,
    const unsigned short* __restrict__ Vt, float* __restrict__ po,
    float* __restrict__ pm, float* __restrict__ pl)
{
    __shared__ unsigned short P16[4][16][72];
    int bid = blockIdx.x;
    int ksl = bid & 3;
    int h = (bid >> 2) & 3;
    int qb = bid >> 4;
    int t = threadIdx.x;
    int w = t >> 6;
    int l = t & 63;
    int lg = l >> 4, lc = l & 15;
    int q0 = (qb * 4 + w) * 16;
    f32x4 zero = {0.f, 0.f, 0.f, 0.f};
    const unsigned short* Qh = Qb + h * 131072;
    const unsigned short* Kh = Kb + h * 131072;
    const unsigned short* Vh = Vt + h * 131072;
    bf16x8 qf = *(const bf16x8*)(Qh + (size_t)(q0 + lc) * 32 + lg * 8);
    f32x4 o0 = zero, o1 = zero;
    float mx[4] = {-1e30f, -1e30f, -1e30f, -1e30f};
    float ls[4] = {0.f, 0.f, 0.f, 0.f};
    int kbeg = ksl * KSLEN;
    #pragma unroll 1
    for (int kt = kbeg; kt < kbeg + KSLEN; kt += 64) {
        f32x4 s[4];
        #pragma unroll
        for (int sub = 0; sub < 4; sub++) {
            bf16x8 kf = *(const bf16x8*)(Kh + (size_t)(kt + sub * 16 + lc) * 32 + lg * 8);
            s[sub] = __builtin_amdgcn_mfma_f32_16x16x32_bf16(qf, kf, zero, 0, 0, 0);
        }
        bf16x8 vf[2][2];
        #pragma unroll
        for (int ks = 0; ks < 2; ks++)
            #pragma unroll
            for (int ct = 0; ct < 2; ct++)
                vf[ks][ct] = *(const bf16x8*)(Vh + (size_t)(ct * 16 + lc) * 4096 + kt + ks * 32 + lg * 8);
        float p_[4][4];
        #pragma unroll
        for (int r = 0; r < 4; r++) {
            float tm = fmaxf(fmaxf(s[0][r], s[1][r]), fmaxf(s[2][r], s[3][r]));
            tm = fmaxf(tm, __shfl_xor(tm, 1));
            tm = fmaxf(tm, __shfl_xor(tm, 2));
            tm = fmaxf(tm, __shfl_xor(tm, 4));
            tm = fmaxf(tm, __shfl_xor(tm, 8));
            if (tm > mx[r]) {
                float cr = __expf(mx[r] - tm);
                ls[r] *= cr;
                o0[r] *= cr;
                o1[r] *= cr;
                mx[r] = tm;
            }
            float rs = 0.f;
            #pragma unroll
            for (int sub = 0; sub < 4; sub++) {
                p_[sub][r] = __expf(s[sub][r] - mx[r]);
                rs += p_[sub][r];
            }
            rs += __shfl_xor(rs, 1);
            rs += __shfl_xor(rs, 2);
            rs += __shfl_xor(rs, 4);
            rs += __shfl_xor(rs, 8);
            ls[r] += rs;
        }
        #pragma unroll
        for (int sub = 0; sub < 4; sub++)
            #pragma unroll
            for (int r = 0; r < 4; r++)
                P16[w][lg * 4 + r][sub * 16 + lc] = f2bf(p_[sub][r]);
        bf16x8 pa[2];
        #pragma unroll
        for (int ks = 0; ks < 2; ks++)
            pa[ks] = *(const bf16x8*)(&P16[w][lc][ks * 32 + lg * 8]);
        #pragma unroll
        for (int ks = 0; ks < 2; ks++) {
            o0 = __builtin_amdgcn_mfma_f32_16x16x32_bf16(pa[ks], vf[ks][0], o0, 0, 0, 0);
            o1 = __builtin_amdgcn_mfma_f32_16x16x32_bf16(pa[ks], vf[ks][1], o1, 0, 0, 0);
        }
    }
    int base0 = (ksl * HHH + h) * NN + q0;
    #pragma unroll
    for (int r = 0; r < 4; r++) {
        size_t ob = (size_t)(base0 + lg * 4 + r) * 32;
        po[ob + lc] = o0[r];
        po[ob + 16 + lc] = o1[r];
    }
    #pragma unroll
    for (int r = 0; r < 4; r++) {
        if (lc == r) {
            pm[base0 + lg * 4 + r] = mx[r];
            pl[base0 + lg * 4 + r] = ls[r];
        }
    }
}

__global__ __launch_bounds__(256) void attn_comb(
    const float* __restrict__ po, const float* __restrict__ pm, const float* __restrict__ pl,
    float* __restrict__ o_at)
{
    int idx = blockIdx.x * 256 + threadIdx.x;  // N*128
    int n = idx >> 7, hc = idx & 127, hh = hc >> 5, c = idx & 31;
    float M = -1e30f;
    #pragma unroll
    for (int s = 0; s < KSLICES; s++) M = fmaxf(M, pm[(s * HHH + hh) * NN + n]);
    float accv = 0.f, L = 0.f;
    #pragma unroll
    for (int s = 0; s < KSLICES; s++) {
        int id = (s * HHH + hh) * NN + n;
        float wgt = __expf(pm[id] - M);
        L = fmaf(wgt, pl[id], L);
        accv = fmaf(wgt, po[(size_t)id * 32 + c], accv);
    }
    o_at[idx] = accv / L;
}

// ---------------- combine; final (BN from raw sums) ----------------
__global__ __launch_bounds__(256) void combine_kernel(
    const float* __restrict__ y1, const float* __restrict__ y2,
    const float* __restrict__ stats,
    const float* __restrict__ g1, const float* __restrict__ be1,
    const float* __restrict__ g2, const float* __restrict__ be2,
    float* __restrict__ outp)
{
    int idx = blockIdx.x * 256 + threadIdx.x;
    int c = idx & 127;
    const float invn = 1.f / (float)NN;
    float mu1 = stats[c] * invn;
    float r1 = rsqrtf(stats[128 + c] * invn - mu1 * mu1 + EPSV);
    float mu2 = stats[256 + c] * invn;
    float r2 = rsqrtf(stats[384 + c] * invn - mu2 * mu2 + EPSV);
    float v1 = (y1[idx] - mu1) * r1 * g1[c] + be1[c];
    float v2 = (y2[idx] - mu2) * r2 * g2[c] + be2[c];
    outp[idx] = v1 + v2;
}

__global__ __launch_bounds__(256) void final_kernel(
    const float* __restrict__ out2, const float* __restrict__ stats,
    const float* __restrict__ g3, const float* __restrict__ be3,
    float* __restrict__ outv)
{
    int idx = blockIdx.x * 256 + threadIdx.x;
    int c = idx & 127;
    const float invn = 1.f / (float)NN;
    float mu = stats[512 + c] * invn;
    float r = rsqrtf(stats[640 + c] * invn - mu * mu + EPSV);
    outv[idx] = (out2[idx] - mu) * r * g3[c] + be3[c];
}

extern "C" void kernel_launch(void* const* d_in, const int* in_sizes, int n_in,
                              void* d_out, int out_size, void* d_ws, size_t ws_size,
                              hipStream_t stream)
{
    (void)in_sizes; (void)n_in; (void)out_size; (void)ws_size;
    const float* x_a   = (const float*)d_in[0];
    const float* x_b   = (const float*)d_in[1];
    const float* x_c   = (const float*)d_in[2];
    const int* ab_s    = (const int*)d_in[3];
    const int* ab_d    = (const int*)d_in[4];
    const int* ac_s    = (const int*)d_in[5];
    const int* ac_d    = (const int*)d_in[6];
    const int* cb_s    = (const int*)d_in[7];
    const int* cb_d    = (const int*)d_in[8];
    const float* W_in_a = (const float*)d_in[9];
    const float* b_in_a = (const float*)d_in[10];
    const float* W_in_b = (const float*)d_in[11];
    const float* b_in_b = (const float*)d_in[12];
    const float* W_in_c = (const float*)d_in[13];
    const float* b_in_c = (const float*)d_in[14];
    const float* W_gat  = (const float*)d_in[15];
    const float* att_src = (const float*)d_in[16];
    const float* att_dst = (const float*)d_in[17];
    const float* b_gat  = (const float*)d_in[18];
    const float* W_qkv  = (const float*)d_in[19];
    const float* b_qkv  = (const float*)d_in[20];
    const float* W_o    = (const float*)d_in[21];
    const float* b_o    = (const float*)d_in[22];
    const float* g1     = (const float*)d_in[23];
    const float* be1    = (const float*)d_in[24];
    const float* g2     = (const float*)d_in[25];
    const float* be2    = (const float*)d_in[26];
    const float* g3     = (const float*)d_in[27];
    const float* be3    = (const float*)d_in[28];
    const float* W_mlp1 = (const float*)d_in[29];
    const float* b_mlp1 = (const float*)d_in[30];
    const float* W_mlp2 = (const float*)d_in[31];
    const float* b_mlp2 = (const float*)d_in[32];

    float* ws   = (float*)d_ws;
    float* h    = ws + 0;          // 524288
    float* o_at = ws + 2097152;    // 524288
    float* y2   = ws + 2621440;    // 524288 (attn-time: pm/pl; later: o-proj+res)
    float* stats = ws + 3145728;   // 768 (raw sums; zeroed each launch)
    float* R    = ws + 3146496;    // reused region
    // attention-time views:
    float* po = R;                        // 4*4*4096*32 = 2097152 floats
    unsigned short* Qb = (unsigned short*)(R + 2097152);  // 262144 bf16
    unsigned short* Kb = (unsigned short*)(R + 2228224);
    unsigned short* Vt = (unsigned short*)(R + 2359296);
    float* pm = y2;                // 65536
    float* pl = y2 + 65536;        // 65536
    // post-attention view of R:
    float* xp   = R + 0;           // 524288
    float* y1   = R + 524288;      // 524288
    float* outp = R + 1048576;     // 524288
    float* hid  = R + 1572864;     // 1048576
    float* out2 = R + 2621440;     // 524288
    float* asv  = R + 3145728;     // 16384
    float* adv  = R + 3162112;     // 16384
    int* cnt    = (int*)(R + 3178496);
    int* rowptr = cnt + 4096;      // 4104 incl pad
    int* fill   = rowptr + 4104;
    int* csr    = fill + 4096;     // E_TOT

    hipMemsetAsync(stats, 0, 768 * sizeof(float), stream);

    // ---- fused input projections + qkv (qkv GEMM packs bf16 Q/K/V directly) ----
    proj3_kernel<<<dim3(2, 64), 256, 0, stream>>>(x_a, W_in_a, b_in_a, x_b, W_in_b, b_in_b, x_c, W_in_c, b_in_c, h);
    gemm_kernel<<<dim3(6, 64), 256, 0, stream>>>(h, W_qkv, b_qkv, nullptr, nullptr, NN, 384, 128, 1, 0, nullptr, Qb, Kb, Vt);
    // ---- global attention (MFMA flash, online-max) ----
    attn_kernel<<<64 * HHH * KSLICES, 256, 0, stream>>>(Qb, Kb, Vt, po, pm, pl);
    attn_comb<<<NN * 128 / 256, 256, 0, stream>>>(po, pm, pl, o_at);
    gemm_kernel<<<dim3(2, 64), 256, 0, stream>>>(o_at, W_o, b_o, h, y2, NN, 128, 128, 1, 0, stats + 256, nullptr, nullptr, nullptr);
    // ---- GAT branch (W_gat via MFMA bf16; att-scores fused into its epilogue) ----
    mgemm_kernel<<<dim3(2, 64), 256, 0, stream>>>(h, W_gat, nullptr, nullptr, xp, NN, 128, 128, 0, nullptr,
                                                  att_src, att_dst, asv, adv);
    hipMemsetAsync(cnt, 0, NN * sizeof(int), stream);
    edge_hist<<<E_TOT / 256, 256, 0, stream>>>(ab_d, ac_d, cb_d, cnt);
    scan_kernel<<<1, 256, 0, stream>>>(cnt, rowptr, fill);
    edge_scatter<<<E_TOT / 256, 256, 0, stream>>>(ab_s, ab_d, ac_s, ac_d, cb_s, cb_d, fill, csr);
    gat_gather<<<NN, 128, 0, stream>>>(xp, asv, adv, rowptr, csr, b_gat, h, y1);
    bn_acc<<<32, 256, 0, stream>>>(y1, stats + 0);
    // ---- combine + MLP (MFMA bf16 GEMMs) ----
    combine_kernel<<<NN * 128 / 256, 256, 0, stream>>>(y1, y2, stats, g1, be1, g2, be2, outp);
    mgemm_kernel<<<dim3(4, 64), 256, 0, stream>>>(outp, W_mlp1, b_mlp1, nullptr, hid, NN, 256, 128, 1, nullptr,
                                                  nullptr, nullptr, nullptr, nullptr);
    mgemm_kernel<<<dim3(2, 64), 256, 0, stream>>>(hid, W_mlp2, b_mlp2, outp, out2, NN, 128, 256, 0, stats + 512,
                                                  nullptr, nullptr, nullptr, nullptr);
    final_kernel<<<NN * 128 / 256, 256, 0, stream>>>(out2, stats, g3, be3, (float*)d_out);
}